// Round 12
// baseline (229.110 us; speedup 1.0000x reference)
//
#include <hip/hip_runtime.h>
#include <hip/hip_bf16.h>
#include <cmath>

typedef unsigned short u16;
typedef __bf16 bf16_t;
typedef bf16_t bf16x8 __attribute__((ext_vector_type(8)));
typedef bf16_t bf16x2 __attribute__((ext_vector_type(2)));
typedef float f32x4 __attribute__((ext_vector_type(4)));
typedef u16 u16x8 __attribute__((ext_vector_type(8)));
typedef short s16x4 __attribute__((ext_vector_type(4)));

#define MFMA16(A,B,C) __builtin_amdgcn_mfma_f32_16x16x32_bf16(A,B,C,0,0,0)
#define MFMA16K16(A,B,C) __builtin_amdgcn_mfma_f32_16x16x16bf16_1k(A,B,C,0,0,0)

#define CB 512
#define TT 1024
#define NH 8
#define DH 64
// ALPHA = (1/sqrt(512)) * log2(e): folded into qu and corr so exp(score)=exp2(s2)
#define ALPHA (0.044194173824159216f * 1.4426950408889634f)
#define MASKL 14426.950408889634f   // 10000 * log2(e)

// native bf16 convert (RNE; compiler emits v_cvt_pk_bf16_f32)
static __device__ __forceinline__ u16 f2b(float f) {
  union { bf16_t b; u16 u; } r; r.b = (bf16_t)f; return r.u;
}
static __device__ __forceinline__ unsigned cvt2(float lo, float hi) {
  union { bf16x2 v; unsigned u; } r;
  r.v[0] = (bf16_t)lo; r.v[1] = (bf16_t)hi; return r.u;
}
static __device__ __forceinline__ float b2f(u16 u) {
  return __uint_as_float(((unsigned)u) << 16);
}
static __device__ __forceinline__ bf16x8 ldb8(const u16* p) {
  return *reinterpret_cast<const bf16x8*>(p);
}

// ========== merged prefix: convert5 (640) | transpose_pe (256) | ln (128) | wcorr (1) ==========
__global__ __launch_bounds__(256)
void prefix_kernel(const float* __restrict__ Wq, const float* __restrict__ Wk,
                   const float* __restrict__ Wv, const float* __restrict__ Wp,
                   const float* __restrict__ Wo,
                   u16* __restrict__ Wstk, u16* __restrict__ WoB,
                   const float* __restrict__ pe, u16* __restrict__ posT,
                   const float* __restrict__ x, const float* __restrict__ gamma,
                   const float* __restrict__ beta, u16* __restrict__ xnT,
                   const float* __restrict__ ub, const float* __restrict__ vb,
                   float* __restrict__ wcorr)
{
  __shared__ float tile[64][65];                 // transpose; ln/wcorr reuse slices
  const int bid = blockIdx.x;
  const int tid = threadIdx.x;
  if (bid < 640) {
    int i = bid * 256 + tid;
    int sel = i >> 15, loc = i & 32767;
    const float* src = (sel == 0) ? Wq : (sel == 1) ? Wk : (sel == 2) ? Wv
                     : (sel == 3) ? Wp : Wo;
    const float4 a = ((const float4*)src)[loc * 2 + 0];
    const float4 b = ((const float4*)src)[loc * 2 + 1];
    u16x8 o;
    o[0] = f2b(a.x); o[1] = f2b(a.y); o[2] = f2b(a.z); o[3] = f2b(a.w);
    o[4] = f2b(b.x); o[5] = f2b(b.y); o[6] = f2b(b.z); o[7] = f2b(b.w);
    u16* dst = (sel < 4) ? (Wstk + (size_t)i * 8) : (WoB + (size_t)loc * 8);
    *(u16x8*)dst = o;
  } else if (bid < 896) {
    int bb = bid - 640;
    int j0 = (bb & 31) * 64, c0 = (bb >> 5) * 64;
    for (int e = tid; e < 4096; e += 256) {
      int cc = e >> 6, jj = e & 63;
      int j = j0 + jj;
      tile[jj][cc] = (j < 2047) ? pe[(size_t)(c0 + cc) * 2047 + j] : 0.f;
    }
    __syncthreads();
    for (int e = tid; e < 4096; e += 256) {
      int jj = e >> 6, cc = e & 63;
      posT[(size_t)(j0 + jj) * 512 + c0 + cc] = f2b(tile[jj][cc]);
    }
  } else if (bid < 1024) {
    float (*sred)[33]  = (float(*)[33])&tile[0][0];
    float (*ssred)[33] = (float(*)[33])&tile[8][0];
    int bb = bid - 896;
    int tl = tid & 31, cg = tid >> 5;
    int t = (bb & 31) * 32 + tl;
    int b = bb >> 5;
    const float* xb = x + (size_t)b * CB * TT + t;
    float s = 0.f, ss = 0.f;
    for (int c = cg * 64; c < cg * 64 + 64; ++c) {
      float v = xb[(size_t)c * TT];
      s += v; ss += v * v;
    }
    sred[cg][tl] = s; ssred[cg][tl] = ss;
    __syncthreads();
    float S = 0.f, SS = 0.f;
    #pragma unroll
    for (int g = 0; g < 8; ++g) { S += sred[g][tl]; SS += ssred[g][tl]; }
    float mean = S * (1.f / 512.f);
    float var = SS * (1.f / 512.f) - mean * mean;
    float rstd = rsqrtf(var + 1e-5f);
    u16* orow = xnT + ((size_t)b * TT + t) * CB;
    for (int c8 = 0; c8 < 8; ++c8) {
      int c = cg * 64 + c8 * 8;
      u16x8 o;
      #pragma unroll
      for (int j = 0; j < 8; ++j) {
        float v = xb[(size_t)(c + j) * TT];
        o[j] = f2b((v - mean) * rstd * gamma[c + j] + beta[c + j]);
      }
      *(u16x8*)(orow + c) = o;
    }
  } else {
    // wcorr[h][c] = sum_d (vb-ub)[h][d] * Wp[h*64+d][c]
    float* dl2 = &tile[0][0];                  // 512 floats
    for (int i = tid; i < 512; i += 256) dl2[i] = vb[i] - ub[i];
    __syncthreads();
    const int hh = tid >> 5;
    const int c0 = (tid & 31) * 16;
    float acc[16] = {};
    for (int d = 0; d < 64; ++d) {
      const float dv = dl2[hh * 64 + d];
      const float* wrow = Wp + (size_t)(hh * 64 + d) * 512 + c0;
      #pragma unroll
      for (int j = 0; j < 16; ++j) acc[j] += dv * wrow[j];
    }
    #pragma unroll
    for (int j = 0; j < 16; ++j) wcorr[hh * 512 + c0 + j] = acc[j];
  }
}

// ========== merged projections: q/k/v (768) | p (256) | corr (64) ==========
__global__ __launch_bounds__(256)
void proj_kernel(const u16* __restrict__ Wstk, const u16* __restrict__ xnT,
                 const u16* __restrict__ posT,
                 const float* __restrict__ bq, const float* __restrict__ ub,
                 const float* __restrict__ bk, const float* __restrict__ bv,
                 const float* __restrict__ wcorr,
                 u16* __restrict__ quB, u16* __restrict__ kB, u16* __restrict__ vB,
                 u16* __restrict__ pB, float* __restrict__ corrOut)
{
  __shared__ float wc[512];
  const int bid = blockIdx.x;
  const int tid = threadIdx.x, w = tid >> 6, lane = tid & 63;
  const int ln16 = lane & 15, kg = lane >> 4;
  if (bid < 768) {
    const int bx = bid & 7;
    const int t = bid >> 3;
    const int my = t % 24;
    const int z = t / 24;
    const int wm = w & 1, wn = w >> 1;
    const int sec = my >> 3;
    const int m0l = (my & 7) * 64 + wm * 32;
    const int n0 = bx * 128 + wn * 64;
    const long XS = (long)TT * CB;
    const long QS = (long)NH * TT * DH;
    const u16* Ar = Wstk + (size_t)(sec * 512 + m0l + ln16) * 512 + kg * 8;
    const u16* Br = xnT + (size_t)z * XS + (size_t)(n0 + ln16) * 512 + kg * 8;
    f32x4 acc[2][4] = {};
    #pragma unroll 2
    for (int ks = 0; ks < 16; ++ks) {
      bf16x8 a[2], bb[4];
      #pragma unroll
      for (int mt = 0; mt < 2; ++mt) a[mt] = ldb8(Ar + (size_t)mt * 16 * 512 + ks * 32);
      #pragma unroll
      for (int nt = 0; nt < 4; ++nt) bb[nt] = ldb8(Br + (size_t)nt * 16 * 512 + ks * 32);
      #pragma unroll
      for (int mt = 0; mt < 2; ++mt)
        #pragma unroll
        for (int nt = 0; nt < 4; ++nt)
          acc[mt][nt] = MFMA16(a[mt], bb[nt], acc[mt][nt]);
    }
    const float scl = (sec == 0) ? ALPHA : 1.f;
    float add[2][4];
    #pragma unroll
    for (int mt = 0; mt < 2; ++mt)
      #pragma unroll
      for (int jr = 0; jr < 4; ++jr) {
        int m = m0l + mt * 16 + kg * 4 + jr;
        add[mt][jr] = (sec == 0) ? (bq[m] + ub[m]) : (sec == 1) ? bk[m] : bv[m];
      }
    if (sec < 2) {
      u16* dst = sec ? kB : quB;
      #pragma unroll
      for (int mt = 0; mt < 2; ++mt)
        #pragma unroll
        for (int nt = 0; nt < 4; ++nt) {
          const int n = n0 + nt * 16 + ln16;
          const int m_low = m0l + mt * 16;
          const size_t o = (size_t)z * QS +
                           ((size_t)(m_low >> 6) * TT + n) * 64 + (m_low & 63) + kg * 4;
          uint2 o2;
          o2.x = cvt2((acc[mt][nt][0] + add[mt][0]) * scl,
                      (acc[mt][nt][1] + add[mt][1]) * scl);
          o2.y = cvt2((acc[mt][nt][2] + add[mt][2]) * scl,
                      (acc[mt][nt][3] + add[mt][3]) * scl);
          *reinterpret_cast<uint2*>(dst + o) = o2;
        }
    } else {
      #pragma unroll
      for (int mt = 0; mt < 2; ++mt)
        #pragma unroll
        for (int nt = 0; nt < 4; ++nt) {
          const int n = n0 + nt * 16 + ln16;
          #pragma unroll
          for (int jr = 0; jr < 4; ++jr)
            vB[(size_t)z * QS + (size_t)(m0l + mt * 16 + kg * 4 + jr) * TT + n] =
                f2b(acc[mt][nt][jr] + add[mt][jr]);
        }
    }
  } else if (bid < 1024) {
    // p projection: pB[h][2048][64] (OMODE-1 layout, no bias)
    const int i = bid - 768;
    const int m0 = (i >> 5) * 64 + (w & 1) * 32;
    const int n0 = (i & 31) * 64 + (w >> 1) * 32;
    const u16* Ar = Wstk + (size_t)(1536 + m0 + ln16) * 512 + kg * 8;
    const u16* Br = posT + (size_t)(n0 + ln16) * 512 + kg * 8;
    f32x4 acc[2][2] = {};
    #pragma unroll 2
    for (int ks = 0; ks < 16; ++ks) {
      bf16x8 a[2], bb[2];
      #pragma unroll
      for (int mt = 0; mt < 2; ++mt) a[mt] = ldb8(Ar + (size_t)mt * 16 * 512 + ks * 32);
      #pragma unroll
      for (int nt = 0; nt < 2; ++nt) bb[nt] = ldb8(Br + (size_t)nt * 16 * 512 + ks * 32);
      #pragma unroll
      for (int mt = 0; mt < 2; ++mt)
        #pragma unroll
        for (int nt = 0; nt < 2; ++nt)
          acc[mt][nt] = MFMA16(a[mt], bb[nt], acc[mt][nt]);
    }
    #pragma unroll
    for (int mt = 0; mt < 2; ++mt)
      #pragma unroll
      for (int nt = 0; nt < 2; ++nt) {
        const int n = n0 + nt * 16 + ln16;
        const int m_low = m0 + mt * 16;
        const size_t o = ((size_t)(m_low >> 6) * 2048 + n) * 64 + (m_low & 63) + kg * 4;
        uint2 o2;
        o2.x = cvt2(acc[mt][nt][0], acc[mt][nt][1]);
        o2.y = cvt2(acc[mt][nt][2], acc[mt][nt][3]);
        *reinterpret_cast<uint2*>(pB + o) = o2;
      }
  } else {
    // corr[h][j] = ALPHA * sum_c wcorr[h][c] * posT[j][c]
    const int i = bid - 1024;
    const int hh = i >> 3;
    const int j = (i & 7) * 256 + tid;
    for (int c = tid; c < 512; c += 256) wc[c] = wcorr[hh * 512 + c];
    __syncthreads();
    const u16* prow = posT + (size_t)j * 512;
    float s = 0.f;
    #pragma unroll 4
    for (int c8 = 0; c8 < 64; ++c8) {
      union { bf16x8 v; u16 u[8]; } pu;
      pu.v = ldb8(prow + c8 * 8);
      #pragma unroll
      for (int e = 0; e < 8; ++e) s += b2f(pu.u[e]) * wc[c8 * 8 + e];
    }
    corrOut[hh * 2048 + j] = s * ALPHA;
  }
}

// ---------- gemm2: wave 32m x 64n, block 64m x 128n (out projection) ----------
template<int K, int OMODE>
__global__ __launch_bounds__(256)
void gemm2(const u16* __restrict__ A, const u16* __restrict__ XT,
           long xStride, long oStride, int Nout,
           const float* __restrict__ b0, void* __restrict__ outv)
{
  const int tid = threadIdx.x, w = tid >> 6, lane = tid & 63;
  const int ln16 = lane & 15, kg = lane >> 4;
  const int wm = w & 1, wn = w >> 1;
  const int m0 = blockIdx.y * 64 + wm * 32;
  const int n0 = blockIdx.x * 128 + wn * 64;
  const int z = blockIdx.z;
  const u16* Ar = A + (size_t)(m0 + ln16) * K + kg * 8;
  const u16* Br = XT + (size_t)z * xStride + (size_t)(n0 + ln16) * K + kg * 8;
  f32x4 acc[2][4] = {};
  #pragma unroll 2
  for (int ks = 0; ks < K / 32; ++ks) {
    bf16x8 a[2], bb[4];
    #pragma unroll
    for (int mt = 0; mt < 2; ++mt) a[mt] = ldb8(Ar + (size_t)mt * 16 * K + ks * 32);
    #pragma unroll
    for (int nt = 0; nt < 4; ++nt) bb[nt] = ldb8(Br + (size_t)nt * 16 * K + ks * 32);
    #pragma unroll
    for (int mt = 0; mt < 2; ++mt)
      #pragma unroll
      for (int nt = 0; nt < 4; ++nt)
        acc[mt][nt] = MFMA16(a[mt], bb[nt], acc[mt][nt]);
  }
  float add[2][4];
  #pragma unroll
  for (int mt = 0; mt < 2; ++mt)
    #pragma unroll
    for (int jr = 0; jr < 4; ++jr)
      add[mt][jr] = b0 ? b0[m0 + mt * 16 + kg * 4 + jr] : 0.f;
  #pragma unroll
  for (int mt = 0; mt < 2; ++mt)
    #pragma unroll
    for (int nt = 0; nt < 4; ++nt) {
      const int n = n0 + nt * 16 + ln16;
      if constexpr (OMODE == 0) {
        float* out = (float*)outv;
        #pragma unroll
        for (int jr = 0; jr < 4; ++jr)
          out[(size_t)z * oStride + (size_t)(m0 + mt * 16 + kg * 4 + jr) * Nout + n] =
              acc[mt][nt][jr] + add[mt][jr];
      } else {
        const int m_low = m0 + mt * 16;
        const size_t o = (size_t)z * oStride +
                         ((size_t)(m_low >> 6) * Nout + n) * 64 + (m_low & 63) + kg * 4;
        uint2 o2;
        o2.x = cvt2(acc[mt][nt][0] + add[mt][0], acc[mt][nt][1] + add[mt][1]);
        o2.y = cvt2(acc[mt][nt][2] + add[mt][2], acc[mt][nt][3] + add[mt][3]);
        *reinterpret_cast<uint2*>((u16*)outv + o) = o2;
      }
    }
}

// ---------- Pass 1 (MFMA): partial l over a ki half (LDS G band) ----------
__global__ __launch_bounds__(256)
void stats_mfma(const u16* __restrict__ qu, const u16* __restrict__ kk_,
                const u16* __restrict__ pp, const float* __restrict__ corr,
                const float* __restrict__ xmask, float* __restrict__ ls)
{
  const int tid = threadIdx.x;
  const int w = tid >> 6, lane = tid & 63;
  const int ln16 = lane & 15, kg = lane >> 4;
  const int bid = blockIdx.x;
  const int bh = (bid & 7) + 8 * ((bid >> 3) & 3);
  const int rest = bid >> 5;
  const int qi0 = (rest & 31) * 32;
  const int part = rest >> 5;
  const int b = bh >> 3, h = bh & 7;
  const u16* quP = qu + (size_t)bh * TT * DH;
  const u16* kP  = kk_ + (size_t)bh * TT * DH;
  const u16* pP  = pp + (size_t)h * 2048 * DH;
  const float* corrP = corr + (h << 11);

  __shared__ u16 G[4][32][100];
  __shared__ float red[4][32];

  bf16x8 qa[2][2];
  #pragma unroll
  for (int mt = 0; mt < 2; ++mt)
    #pragma unroll
    for (int kc = 0; kc < 2; ++kc)
      qa[mt][kc] = ldb8(&quP[(size_t)(qi0 + mt * 16 + ln16) * DH + kc * 32 + kg * 8]);
  float aq[2][4];
  #pragma unroll
  for (int mt = 0; mt < 2; ++mt)
    #pragma unroll
    for (int jr = 0; jr < 4; ++jr)
      aq[mt][jr] = (xmask[b * TT + qi0 + mt * 16 + kg * 4 + jr] - 1.f) * MASKL;

  float rs[2][4] = {};
  for (int c = 0; c < 2; ++c) {
    const int ki0 = (part * 8 + c * 4 + w) * 64;
    const int j0 = ki0 - qi0 + 992;
    #pragma unroll
    for (int nt = 0; nt < 6; ++nt) {
      const size_t po = (size_t)(j0 + nt * 16 + ln16) * DH + kg * 8;
      bf16x8 pb0 = ldb8(&pP[po]);
      bf16x8 pb1 = ldb8(&pP[po + 32]);
      const float cval = corrP[j0 + nt * 16 + ln16];
      #pragma unroll
      for (int mt = 0; mt < 2; ++mt) {
        f32x4 g = {0.f, 0.f, 0.f, 0.f};
        g = MFMA16(qa[mt][0], pb0, g);
        g = MFMA16(qa[mt][1], pb1, g);
        #pragma unroll
        for (int jr = 0; jr < 4; ++jr)
          G[w][mt * 16 + kg * 4 + jr][nt * 16 + ln16] = f2b(g[jr] + cval);
      }
    }
    #pragma unroll
    for (int nt = 0; nt < 4; ++nt) {
      const size_t ko = (size_t)(ki0 + nt * 16 + ln16) * DH + kg * 8;
      bf16x8 kb0 = ldb8(&kP[ko]);
      bf16x8 kb1 = ldb8(&kP[ko + 32]);
      const float ak = (xmask[b * TT + ki0 + nt * 16 + ln16] - 1.f) * MASKL;
      #pragma unroll
      for (int mt = 0; mt < 2; ++mt) {
        f32x4 dd = { aq[mt][0] + ak, aq[mt][1] + ak, aq[mt][2] + ak, aq[mt][3] + ak };
        dd = MFMA16(qa[mt][0], kb0, dd);
        dd = MFMA16(qa[mt][1], kb1, dd);
        #pragma unroll
        for (int jr = 0; jr < 4; ++jr) {
          const int qrow = mt * 16 + kg * 4 + jr;
          const int u = nt * 16 + ln16 - qrow + 31;
          rs[mt][jr] += exp2f(dd[jr] + b2f(G[w][qrow][u]));
        }
      }
    }
  }
  #pragma unroll
  for (int mt = 0; mt < 2; ++mt)
    #pragma unroll
    for (int jr = 0; jr < 4; ++jr) {
      float v = rs[mt][jr];
      v += __shfl_xor(v, 1); v += __shfl_xor(v, 2);
      v += __shfl_xor(v, 4); v += __shfl_xor(v, 8);
      rs[mt][jr] = v;
    }
  if (ln16 == 0) {
    #pragma unroll
    for (int mt = 0; mt < 2; ++mt)
      #pragma unroll
      for (int jr = 0; jr < 4; ++jr)
        red[w][mt * 16 + kg * 4 + jr] = rs[mt][jr];
  }
  __syncthreads();
  if (tid < 32)
    ls[(size_t)part * 32768 + (size_t)bh * TT + qi0 + tid] =
        red[0][tid] + red[1][tid] + red[2][tid] + red[3][tid];
}

// ---------- Pass 2 (MFMA): barrier-free per-wave PV (K=16 identity mapping) ----------
// Each wave owns 16 qi per chunk; its score D-regs feed PV's B-operand directly.
// Cross-wave d-sum done once at block end via LDS (2 rounds).
__global__ __launch_bounds__(256)
void ctx_mfma(const u16* __restrict__ qu, const u16* __restrict__ kk_,
              const u16* __restrict__ vv, const u16* __restrict__ pp,
              const float* __restrict__ corr, const float* __restrict__ xmask,
              u16* __restrict__ ctx2)
{
  const int tid = threadIdx.x;
  const int w = tid >> 6, lane = tid & 63;
  const int ln16 = lane & 15, kg = lane >> 4;
  const int l48 = lane & 48;
  const int bid = blockIdx.x;
  const int bh = (bid & 7) + 8 * ((bid >> 3) & 3);
  const int rest = bid >> 5;
  const int t0 = (rest & 15) * 64;
  const int part = rest >> 4;
  const int b = bh >> 3, h = bh & 7;
  const u16* quP = qu + (size_t)bh * TT * DH;
  const u16* kP  = kk_ + (size_t)bh * TT * DH;
  const u16* vP  = vv + (size_t)bh * DH * TT;
  const u16* pP  = pp + (size_t)h * 2048 * DH;
  const float* corrP = corr + (h << 11);

  __shared__ float buf[4][2][64][4][4];        // 32 KiB reduction buffer

  bf16x8 ka[4][2];
  #pragma unroll
  for (int nt = 0; nt < 4; ++nt)
    #pragma unroll
    for (int kc = 0; kc < 2; ++kc)
      ka[nt][kc] = ldb8(&kP[(size_t)(t0 + nt * 16 + ln16) * DH + kc * 32 + kg * 8]);
  float at4[4];
  #pragma unroll
  for (int nt = 0; nt < 4; ++nt)
    at4[nt] = (xmask[b * TT + t0 + nt * 16 + ln16] - 1.f) * MASKL;

  f32x4 cacc[4][4] = {};                       // [d-frag][nt]
  for (int qc = part * 4; qc < part * 4 + 4; ++qc) {
    const int qw = qc * 64 + w * 16;
    const int j0 = t0 - qw + 1008;
    const size_t qo = (size_t)(qw + ln16) * DH + kg * 8;
    bf16x8 qa0 = ldb8(&quP[qo]), qa1 = ldb8(&quP[qo + 32]);
    // v A-frags (K=16) for the 4 d-frags of this chunk
    s16x4 vfr[4];
    #pragma unroll
    for (int df = 0; df < 4; ++df)
      vfr[df] = *reinterpret_cast<const s16x4*>(
          &vP[(size_t)(df * 16 + ln16) * TT + qw + kg * 4]);
    // pos bands in registers; shuffle each band immediately
    float sg[4][5];
    #pragma unroll
    for (int n = 0; n < 5; ++n) {
      const size_t po = (size_t)(j0 + n * 16 + ln16) * DH + kg * 8;
      bf16x8 pb0 = ldb8(&pP[po]), pb1 = ldb8(&pP[po + 32]);
      const float cval = corrP[j0 + n * 16 + ln16];
      f32x4 g = {cval, cval, cval, cval};
      g = MFMA16(qa0, pb0, g);
      g = MFMA16(qa1, pb1, g);
      #pragma unroll
      for (int jr = 0; jr < 4; ++jr) {
        const int src = l48 | ((ln16 + 15 - (kg * 4 + jr)) & 15);
        sg[jr][n] = __shfl(g[jr], src);
      }
    }
    float aqv[4];
    #pragma unroll
    for (int jr = 0; jr < 4; ++jr)
      aqv[jr] = (xmask[b * TT + qw + kg * 4 + jr] - 1.f) * MASKL;
    #pragma unroll
    for (int nt = 0; nt < 4; ++nt) {
      f32x4 dd = { aqv[0] + at4[nt], aqv[1] + at4[nt],
                   aqv[2] + at4[nt], aqv[3] + at4[nt] };
      dd = MFMA16(qa0, ka[nt][0], dd);
      dd = MFMA16(qa1, ka[nt][1], dd);
      float ev[4];
      #pragma unroll
      for (int jr = 0; jr < 4; ++jr) {
        const int qrow = kg * 4 + jr;
        const float val = (ln16 <= qrow) ? sg[jr][nt] : sg[jr][nt + 1];
        ev[jr] = exp2f(dd[jr] + val);
      }
      union { uint2 u; s16x4 s; } pa;
      pa.u = make_uint2(cvt2(ev[0], ev[1]), cvt2(ev[2], ev[3]));
      #pragma unroll
      for (int df = 0; df < 4; ++df)
        cacc[df][nt] = MFMA16K16(vfr[df], pa.s, cacc[df][nt]);
    }
  }
  // cross-wave reduction: 2 rounds x 2 d-frags
  #pragma unroll
  for (int r = 0; r < 2; ++r) {
    if (r) __syncthreads();                    // buf reuse guard
    #pragma unroll
    for (int y = 0; y < 2; ++y)
      #pragma unroll
      for (int nt = 0; nt < 4; ++nt)
        #pragma unroll
        for (int jr = 0; jr < 4; ++jr)
          buf[w][y][lane][nt][jr] = cacc[r * 2 + y][nt][jr];
    __syncthreads();
    if (w < 2) {
      const int df = r * 2 + w;
      #pragma unroll
      for (int nt = 0; nt < 4; ++nt) {
        float s0 = buf[0][w][lane][nt][0] + buf[1][w][lane][nt][0] +
                   buf[2][w][lane][nt][0] + buf[3][w][lane][nt][0];
        float s1 = buf[0][w][lane][nt][1] + buf[1][w][lane][nt][1] +
                   buf[2][w][lane][nt][1] + buf[3][w][lane][nt][1];
        float s2 = buf[0][w][lane][nt][2] + buf[1][w][lane][nt][2] +
                   buf[2][w][lane][nt][2] + buf[3][w][lane][nt][2];
        float s3 = buf[0][w][lane][nt][3] + buf[1][w][lane][nt][3] +
                   buf[2][w][lane][nt][3] + buf[3][w][lane][nt][3];
        const int t = t0 + nt * 16 + ln16;
        uint2 o2;
        o2.x = cvt2(s0, s1);
        o2.y = cvt2(s2, s3);
        *reinterpret_cast<uint2*>(
          &ctx2[((size_t)b * TT + t) * 2048 + part * 512 + h * 64 + df * 16 + kg * 4]) = o2;
      }
    }
  }
}

// ---------- fold 1/l into v (in-place; vB fully rewritten every launch) ----------
__global__ __launch_bounds__(256)
void vscale(u16* __restrict__ vv, const float* __restrict__ ls)
{
  int i = blockIdx.x * 256 + threadIdx.x;     // 262144 groups of 8
  int bh = i >> 13;
  int rem = i & 8191;
  int d = rem >> 7;
  int qi0 = (rem & 127) * 8;
  const float* lsP = ls + bh * 1024 + qi0;
  u16* row = vv + ((size_t)bh * 64 + d) * 1024 + qi0;
  union { u16x8 v; u16 u[8]; } t;
  t.v = *(u16x8*)row;
  u16x8 o;
  #pragma unroll
  for (int e = 0; e < 8; ++e) {
    float linv = __builtin_amdgcn_rcpf(lsP[e] + lsP[32768 + e]);
    o[e] = f2b(b2f(t.u[e]) * linv);
  }
  *(u16x8*)row = o;
}

// ---------- sum 4 ctx partials -> ctxS [b][t][512] bf16 ----------
__global__ __launch_bounds__(256)
void reduce_ctx(const u16* __restrict__ ctx2, u16* __restrict__ ctxS)
{
  int i = blockIdx.x * 256 + threadIdx.x;      // 262144 groups of 8
  int row = i >> 6;
  int c0 = (i & 63) * 8;
  const u16* src = ctx2 + (size_t)row * 2048 + c0;
  float s[8] = {};
  #pragma unroll
  for (int p = 0; p < 4; ++p) {
    union { u16x8 v; u16 u[8]; } t;
    t.v = *(const u16x8*)(src + p * 512);
    #pragma unroll
    for (int e = 0; e < 8; ++e) s[e] += b2f(t.u[e]);
  }
  u16x8 o;
  #pragma unroll
  for (int e = 0; e < 8; ++e) o[e] = f2b(s[e]);
  *(u16x8*)(ctxS + (size_t)row * 512 + c0) = o;
}

// ---------- launch ----------
extern "C" void kernel_launch(void* const* d_in, const int* in_sizes, int n_in,
                              void* d_out, int out_size, void* d_ws, size_t ws_size,
                              hipStream_t stream)
{
  (void)in_sizes; (void)n_in; (void)out_size;
  const float* x     = (const float*)d_in[0];
  const float* pe    = (const float*)d_in[1];
  const float* xm    = (const float*)d_in[2];
  const float* gamma = (const float*)d_in[3];
  const float* beta  = (const float*)d_in[4];
  const float* Wq    = (const float*)d_in[5];
  const float* bq    = (const float*)d_in[6];
  const float* Wk    = (const float*)d_in[7];
  const float* bk    = (const float*)d_in[8];
  const float* Wv    = (const float*)d_in[9];
  const float* bv    = (const float*)d_in[10];
  const float* Wp    = (const float*)d_in[11];
  const float* ub    = (const float*)d_in[12];
  const float* vb    = (const float*)d_in[13];
  const float* Wo    = (const float*)d_in[14];
  const float* bo    = (const float*)d_in[15];

  // workspace layout (bytes), total 32,309,248 <= 33,882,112 known-safe
  char* ws = (char*)d_ws;
  u16*  quB  = (u16*) (ws + 0);          // [32][1024][64] bf16  (4 MiB)
  u16*  ctxS = (u16*) (ws + 0);          // [4][1024][512] bf16  (overlay: quB dead)
  u16*  kB   = (u16*) (ws + 4194304);    // [32][1024][64] bf16  (4 MiB)
  u16*  vB   = (u16*) (ws + 8388608);    // [32][64][1024] bf16  (4 MiB)
  u16*  pB   = (u16*) (ws + 12582912);   // [8][2048][64] bf16   (2 MiB)
  float* corrB = (float*)(ws + 14680064);// [8][2048] f32        (64 KiB)
  float* lsB = (float*)(ws + 14745600);  // [2][32][1024] f32    (256 KiB)
  u16*  WoB  = (u16*) (ws + 15007744);   // [512][512] bf16      (512 KiB)
  u16*  ctx2 = (u16*) (ws + 15532032);   // [4][1024][2048] bf16 (16 MiB)
  // staging (dead before ctx2 is written) overlaid inside ctx2's region:
  u16*  xnT  = (u16*) (ws + 15532032);   // [4][1024][512] bf16  (4 MiB)
  u16*  posT = (u16*) (ws + 19726336);   // [2048][512] bf16     (2 MiB)
  u16*  Wstk = (u16*) (ws + 21823488);   // [2048][512] bf16     (2 MiB)
  float* wcorrB = (float*)(ws + 23920640); // [8][512] f32       (16 KiB)
  if (ws_size < 32309248) return;

  dim3 blk(256);

  prefix_kernel<<<dim3(1025), blk, 0, stream>>>(
      Wq, Wk, Wv, Wp, Wo, Wstk, WoB, pe, posT, x, gamma, beta, xnT, ub, vb, wcorrB);
  proj_kernel<<<dim3(1088), blk, 0, stream>>>(
      Wstk, xnT, posT, bq, ub, bk, bv, wcorrB, quB, kB, vB, pB, corrB);

  stats_mfma<<<dim3(2048), blk, 0, stream>>>(quB, kB, pB, corrB, xm, lsB);
  vscale<<<dim3(1024), blk, 0, stream>>>(vB, lsB);
  ctx_mfma<<<dim3(2048), blk, 0, stream>>>(quB, kB, vB, pB, corrB, xm, ctx2);
  reduce_ctx<<<dim3(1024), blk, 0, stream>>>(ctx2, ctxS);

  gemm2<512, 0><<<dim3(8, 8, 4), blk, 0, stream>>>(
      WoB, ctxS, (long)TT * CB, (long)CB * TT, TT, bo, (float*)d_out);
}

// Round 13
// 201.881 us; speedup vs baseline: 1.1349x; 1.1349x over previous
//
#include <hip/hip_runtime.h>
#include <hip/hip_bf16.h>
#include <cmath>

typedef unsigned short u16;
typedef __bf16 bf16_t;
typedef bf16_t bf16x8 __attribute__((ext_vector_type(8)));
typedef bf16_t bf16x2 __attribute__((ext_vector_type(2)));
typedef float f32x4 __attribute__((ext_vector_type(4)));
typedef u16 u16x8 __attribute__((ext_vector_type(8)));

#define MFMA16(A,B,C) __builtin_amdgcn_mfma_f32_16x16x32_bf16(A,B,C,0,0,0)

#define CB 512
#define TT 1024
#define NH 8
#define DH 64
// ALPHA = (1/sqrt(512)) * log2(e): folded into qu and corr so exp(score)=exp2(s2)
#define ALPHA (0.044194173824159216f * 1.4426950408889634f)
#define MASKL 14426.950408889634f   // 10000 * log2(e)

// native bf16 convert (RNE; compiler emits v_cvt_pk_bf16_f32)
static __device__ __forceinline__ u16 f2b(float f) {
  union { bf16_t b; u16 u; } r; r.b = (bf16_t)f; return r.u;
}
static __device__ __forceinline__ unsigned cvt2(float lo, float hi) {
  union { bf16x2 v; unsigned u; } r;
  r.v[0] = (bf16_t)lo; r.v[1] = (bf16_t)hi; return r.u;
}
static __device__ __forceinline__ float b2f(u16 u) {
  return __uint_as_float(((unsigned)u) << 16);
}
static __device__ __forceinline__ bf16x8 ldb8(const u16* p) {
  return *reinterpret_cast<const bf16x8*>(p);
}

// ========== merged prefix: convert5 (640) | transpose_pe (256) | ln (128) | wcorr (1) ==========
__global__ __launch_bounds__(256)
void prefix_kernel(const float* __restrict__ Wq, const float* __restrict__ Wk,
                   const float* __restrict__ Wv, const float* __restrict__ Wp,
                   const float* __restrict__ Wo,
                   u16* __restrict__ Wstk, u16* __restrict__ WoB,
                   const float* __restrict__ pe, u16* __restrict__ posT,
                   const float* __restrict__ x, const float* __restrict__ gamma,
                   const float* __restrict__ beta, u16* __restrict__ xnT,
                   const float* __restrict__ ub, const float* __restrict__ vb,
                   float* __restrict__ wcorr)
{
  __shared__ float tile[64][65];                 // transpose; ln/wcorr reuse slices
  const int bid = blockIdx.x;
  const int tid = threadIdx.x;
  if (bid < 640) {
    int i = bid * 256 + tid;
    int sel = i >> 15, loc = i & 32767;
    const float* src = (sel == 0) ? Wq : (sel == 1) ? Wk : (sel == 2) ? Wv
                     : (sel == 3) ? Wp : Wo;
    const float4 a = ((const float4*)src)[loc * 2 + 0];
    const float4 b = ((const float4*)src)[loc * 2 + 1];
    u16x8 o;
    o[0] = f2b(a.x); o[1] = f2b(a.y); o[2] = f2b(a.z); o[3] = f2b(a.w);
    o[4] = f2b(b.x); o[5] = f2b(b.y); o[6] = f2b(b.z); o[7] = f2b(b.w);
    u16* dst = (sel < 4) ? (Wstk + (size_t)i * 8) : (WoB + (size_t)loc * 8);
    *(u16x8*)dst = o;
  } else if (bid < 896) {
    int bb = bid - 640;
    int j0 = (bb & 31) * 64, c0 = (bb >> 5) * 64;
    for (int e = tid; e < 4096; e += 256) {
      int cc = e >> 6, jj = e & 63;
      int j = j0 + jj;
      tile[jj][cc] = (j < 2047) ? pe[(size_t)(c0 + cc) * 2047 + j] : 0.f;
    }
    __syncthreads();
    for (int e = tid; e < 4096; e += 256) {
      int jj = e >> 6, cc = e & 63;
      posT[(size_t)(j0 + jj) * 512 + c0 + cc] = f2b(tile[jj][cc]);
    }
  } else if (bid < 1024) {
    float (*sred)[33]  = (float(*)[33])&tile[0][0];
    float (*ssred)[33] = (float(*)[33])&tile[8][0];
    int bb = bid - 896;
    int tl = tid & 31, cg = tid >> 5;
    int t = (bb & 31) * 32 + tl;
    int b = bb >> 5;
    const float* xb = x + (size_t)b * CB * TT + t;
    float s = 0.f, ss = 0.f;
    for (int c = cg * 64; c < cg * 64 + 64; ++c) {
      float v = xb[(size_t)c * TT];
      s += v; ss += v * v;
    }
    sred[cg][tl] = s; ssred[cg][tl] = ss;
    __syncthreads();
    float S = 0.f, SS = 0.f;
    #pragma unroll
    for (int g = 0; g < 8; ++g) { S += sred[g][tl]; SS += ssred[g][tl]; }
    float mean = S * (1.f / 512.f);
    float var = SS * (1.f / 512.f) - mean * mean;
    float rstd = rsqrtf(var + 1e-5f);
    u16* orow = xnT + ((size_t)b * TT + t) * CB;
    for (int c8 = 0; c8 < 8; ++c8) {
      int c = cg * 64 + c8 * 8;
      u16x8 o;
      #pragma unroll
      for (int j = 0; j < 8; ++j) {
        float v = xb[(size_t)(c + j) * TT];
        o[j] = f2b((v - mean) * rstd * gamma[c + j] + beta[c + j]);
      }
      *(u16x8*)(orow + c) = o;
    }
  } else {
    // wcorr[h][c] = sum_d (vb-ub)[h][d] * Wp[h*64+d][c]
    float* dl2 = &tile[0][0];                  // 512 floats
    for (int i = tid; i < 512; i += 256) dl2[i] = vb[i] - ub[i];
    __syncthreads();
    const int hh = tid >> 5;
    const int c0 = (tid & 31) * 16;
    float acc[16] = {};
    for (int d = 0; d < 64; ++d) {
      const float dv = dl2[hh * 64 + d];
      const float* wrow = Wp + (size_t)(hh * 64 + d) * 512 + c0;
      #pragma unroll
      for (int j = 0; j < 16; ++j) acc[j] += dv * wrow[j];
    }
    #pragma unroll
    for (int j = 0; j < 16; ++j) wcorr[hh * 512 + c0 + j] = acc[j];
  }
}

// ========== merged projections: q/k/v (768) | p (256) | corr (64) ==========
__global__ __launch_bounds__(256)
void proj_kernel(const u16* __restrict__ Wstk, const u16* __restrict__ xnT,
                 const u16* __restrict__ posT,
                 const float* __restrict__ bq, const float* __restrict__ ub,
                 const float* __restrict__ bk, const float* __restrict__ bv,
                 const float* __restrict__ wcorr,
                 u16* __restrict__ quB, u16* __restrict__ kB, u16* __restrict__ vB,
                 u16* __restrict__ pB, float* __restrict__ corrOut)
{
  __shared__ float wc[512];
  const int bid = blockIdx.x;
  const int tid = threadIdx.x, w = tid >> 6, lane = tid & 63;
  const int ln16 = lane & 15, kg = lane >> 4;
  if (bid < 768) {
    const int bx = bid & 7;
    const int t = bid >> 3;
    const int my = t % 24;
    const int z = t / 24;
    const int wm = w & 1, wn = w >> 1;
    const int sec = my >> 3;
    const int m0l = (my & 7) * 64 + wm * 32;
    const int n0 = bx * 128 + wn * 64;
    const long XS = (long)TT * CB;
    const long QS = (long)NH * TT * DH;
    const u16* Ar = Wstk + (size_t)(sec * 512 + m0l + ln16) * 512 + kg * 8;
    const u16* Br = xnT + (size_t)z * XS + (size_t)(n0 + ln16) * 512 + kg * 8;
    f32x4 acc[2][4] = {};
    #pragma unroll 2
    for (int ks = 0; ks < 16; ++ks) {
      bf16x8 a[2], bb[4];
      #pragma unroll
      for (int mt = 0; mt < 2; ++mt) a[mt] = ldb8(Ar + (size_t)mt * 16 * 512 + ks * 32);
      #pragma unroll
      for (int nt = 0; nt < 4; ++nt) bb[nt] = ldb8(Br + (size_t)nt * 16 * 512 + ks * 32);
      #pragma unroll
      for (int mt = 0; mt < 2; ++mt)
        #pragma unroll
        for (int nt = 0; nt < 4; ++nt)
          acc[mt][nt] = MFMA16(a[mt], bb[nt], acc[mt][nt]);
    }
    const float scl = (sec == 0) ? ALPHA : 1.f;
    float add[2][4];
    #pragma unroll
    for (int mt = 0; mt < 2; ++mt)
      #pragma unroll
      for (int jr = 0; jr < 4; ++jr) {
        int m = m0l + mt * 16 + kg * 4 + jr;
        add[mt][jr] = (sec == 0) ? (bq[m] + ub[m]) : (sec == 1) ? bk[m] : bv[m];
      }
    if (sec < 2) {
      u16* dst = sec ? kB : quB;
      #pragma unroll
      for (int mt = 0; mt < 2; ++mt)
        #pragma unroll
        for (int nt = 0; nt < 4; ++nt) {
          const int n = n0 + nt * 16 + ln16;
          const int m_low = m0l + mt * 16;
          const size_t o = (size_t)z * QS +
                           ((size_t)(m_low >> 6) * TT + n) * 64 + (m_low & 63) + kg * 4;
          uint2 o2;
          o2.x = cvt2((acc[mt][nt][0] + add[mt][0]) * scl,
                      (acc[mt][nt][1] + add[mt][1]) * scl);
          o2.y = cvt2((acc[mt][nt][2] + add[mt][2]) * scl,
                      (acc[mt][nt][3] + add[mt][3]) * scl);
          *reinterpret_cast<uint2*>(dst + o) = o2;
        }
    } else {
      #pragma unroll
      for (int mt = 0; mt < 2; ++mt)
        #pragma unroll
        for (int nt = 0; nt < 4; ++nt) {
          const int n = n0 + nt * 16 + ln16;
          #pragma unroll
          for (int jr = 0; jr < 4; ++jr)
            vB[(size_t)z * QS + (size_t)(m0l + mt * 16 + kg * 4 + jr) * TT + n] =
                f2b(acc[mt][nt][jr] + add[mt][jr]);
        }
    }
  } else if (bid < 1024) {
    // p projection: pB[h][2048][64] (OMODE-1 layout, no bias)
    const int i = bid - 768;
    const int m0 = (i >> 5) * 64 + (w & 1) * 32;
    const int n0 = (i & 31) * 64 + (w >> 1) * 32;
    const u16* Ar = Wstk + (size_t)(1536 + m0 + ln16) * 512 + kg * 8;
    const u16* Br = posT + (size_t)(n0 + ln16) * 512 + kg * 8;
    f32x4 acc[2][2] = {};
    #pragma unroll 2
    for (int ks = 0; ks < 16; ++ks) {
      bf16x8 a[2], bb[2];
      #pragma unroll
      for (int mt = 0; mt < 2; ++mt) a[mt] = ldb8(Ar + (size_t)mt * 16 * 512 + ks * 32);
      #pragma unroll
      for (int nt = 0; nt < 2; ++nt) bb[nt] = ldb8(Br + (size_t)nt * 16 * 512 + ks * 32);
      #pragma unroll
      for (int mt = 0; mt < 2; ++mt)
        #pragma unroll
        for (int nt = 0; nt < 2; ++nt)
          acc[mt][nt] = MFMA16(a[mt], bb[nt], acc[mt][nt]);
    }
    #pragma unroll
    for (int mt = 0; mt < 2; ++mt)
      #pragma unroll
      for (int nt = 0; nt < 2; ++nt) {
        const int n = n0 + nt * 16 + ln16;
        const int m_low = m0 + mt * 16;
        const size_t o = ((size_t)(m_low >> 6) * 2048 + n) * 64 + (m_low & 63) + kg * 4;
        uint2 o2;
        o2.x = cvt2(acc[mt][nt][0], acc[mt][nt][1]);
        o2.y = cvt2(acc[mt][nt][2], acc[mt][nt][3]);
        *reinterpret_cast<uint2*>(pB + o) = o2;
      }
  } else {
    // corr[h][j] = ALPHA * sum_c wcorr[h][c] * posT[j][c]
    const int i = bid - 1024;
    const int hh = i >> 3;
    const int j = (i & 7) * 256 + tid;
    for (int c = tid; c < 512; c += 256) wc[c] = wcorr[hh * 512 + c];
    __syncthreads();
    const u16* prow = posT + (size_t)j * 512;
    float s = 0.f;
    #pragma unroll 4
    for (int c8 = 0; c8 < 64; ++c8) {
      union { bf16x8 v; u16 u[8]; } pu;
      pu.v = ldb8(prow + c8 * 8);
      #pragma unroll
      for (int e = 0; e < 8; ++e) s += b2f(pu.u[e]) * wc[c8 * 8 + e];
    }
    corrOut[hh * 2048 + j] = s * ALPHA;
  }
}

// ---------- gemm2: wave 32m x 64n, block 64m x 128n (out projection) ----------
template<int K, int OMODE>
__global__ __launch_bounds__(256)
void gemm2(const u16* __restrict__ A, const u16* __restrict__ XT,
           long xStride, long oStride, int Nout,
           const float* __restrict__ b0, void* __restrict__ outv)
{
  const int tid = threadIdx.x, w = tid >> 6, lane = tid & 63;
  const int ln16 = lane & 15, kg = lane >> 4;
  const int wm = w & 1, wn = w >> 1;
  const int m0 = blockIdx.y * 64 + wm * 32;
  const int n0 = blockIdx.x * 128 + wn * 64;
  const int z = blockIdx.z;
  const u16* Ar = A + (size_t)(m0 + ln16) * K + kg * 8;
  const u16* Br = XT + (size_t)z * xStride + (size_t)(n0 + ln16) * K + kg * 8;
  f32x4 acc[2][4] = {};
  #pragma unroll 2
  for (int ks = 0; ks < K / 32; ++ks) {
    bf16x8 a[2], bb[4];
    #pragma unroll
    for (int mt = 0; mt < 2; ++mt) a[mt] = ldb8(Ar + (size_t)mt * 16 * K + ks * 32);
    #pragma unroll
    for (int nt = 0; nt < 4; ++nt) bb[nt] = ldb8(Br + (size_t)nt * 16 * K + ks * 32);
    #pragma unroll
    for (int mt = 0; mt < 2; ++mt)
      #pragma unroll
      for (int nt = 0; nt < 4; ++nt)
        acc[mt][nt] = MFMA16(a[mt], bb[nt], acc[mt][nt]);
  }
  float add[2][4];
  #pragma unroll
  for (int mt = 0; mt < 2; ++mt)
    #pragma unroll
    for (int jr = 0; jr < 4; ++jr)
      add[mt][jr] = b0 ? b0[m0 + mt * 16 + kg * 4 + jr] : 0.f;
  #pragma unroll
  for (int mt = 0; mt < 2; ++mt)
    #pragma unroll
    for (int nt = 0; nt < 4; ++nt) {
      const int n = n0 + nt * 16 + ln16;
      if constexpr (OMODE == 0) {
        float* out = (float*)outv;
        #pragma unroll
        for (int jr = 0; jr < 4; ++jr)
          out[(size_t)z * oStride + (size_t)(m0 + mt * 16 + kg * 4 + jr) * Nout + n] =
              acc[mt][nt][jr] + add[mt][jr];
      } else {
        const int m_low = m0 + mt * 16;
        const size_t o = (size_t)z * oStride +
                         ((size_t)(m_low >> 6) * Nout + n) * 64 + (m_low & 63) + kg * 4;
        uint2 o2;
        o2.x = cvt2(acc[mt][nt][0] + add[mt][0], acc[mt][nt][1] + add[mt][1]);
        o2.y = cvt2(acc[mt][nt][2] + add[mt][2], acc[mt][nt][3] + add[mt][3]);
        *reinterpret_cast<uint2*>((u16*)outv + o) = o2;
      }
    }
}

// ---------- Pass 1 (MFMA): partial l over a ki half (LDS G band) ----------
__global__ __launch_bounds__(256)
void stats_mfma(const u16* __restrict__ qu, const u16* __restrict__ kk_,
                const u16* __restrict__ pp, const float* __restrict__ corr,
                const float* __restrict__ xmask, float* __restrict__ ls)
{
  const int tid = threadIdx.x;
  const int w = tid >> 6, lane = tid & 63;
  const int ln16 = lane & 15, kg = lane >> 4;
  const int bid = blockIdx.x;
  const int bh = (bid & 7) + 8 * ((bid >> 3) & 3);
  const int rest = bid >> 5;
  const int qi0 = (rest & 31) * 32;
  const int part = rest >> 5;
  const int b = bh >> 3, h = bh & 7;
  const u16* quP = qu + (size_t)bh * TT * DH;
  const u16* kP  = kk_ + (size_t)bh * TT * DH;
  const u16* pP  = pp + (size_t)h * 2048 * DH;
  const float* corrP = corr + (h << 11);

  __shared__ u16 G[4][32][100];
  __shared__ float red[4][32];

  bf16x8 qa[2][2];
  #pragma unroll
  for (int mt = 0; mt < 2; ++mt)
    #pragma unroll
    for (int kc = 0; kc < 2; ++kc)
      qa[mt][kc] = ldb8(&quP[(size_t)(qi0 + mt * 16 + ln16) * DH + kc * 32 + kg * 8]);
  float aq[2][4];
  #pragma unroll
  for (int mt = 0; mt < 2; ++mt)
    #pragma unroll
    for (int jr = 0; jr < 4; ++jr)
      aq[mt][jr] = (xmask[b * TT + qi0 + mt * 16 + kg * 4 + jr] - 1.f) * MASKL;

  float rs[2][4] = {};
  for (int c = 0; c < 2; ++c) {
    const int ki0 = (part * 8 + c * 4 + w) * 64;
    const int j0 = ki0 - qi0 + 992;
    #pragma unroll
    for (int nt = 0; nt < 6; ++nt) {
      const size_t po = (size_t)(j0 + nt * 16 + ln16) * DH + kg * 8;
      bf16x8 pb0 = ldb8(&pP[po]);
      bf16x8 pb1 = ldb8(&pP[po + 32]);
      const float cval = corrP[j0 + nt * 16 + ln16];
      #pragma unroll
      for (int mt = 0; mt < 2; ++mt) {
        f32x4 g = {0.f, 0.f, 0.f, 0.f};
        g = MFMA16(qa[mt][0], pb0, g);
        g = MFMA16(qa[mt][1], pb1, g);
        #pragma unroll
        for (int jr = 0; jr < 4; ++jr)
          G[w][mt * 16 + kg * 4 + jr][nt * 16 + ln16] = f2b(g[jr] + cval);
      }
    }
    #pragma unroll
    for (int nt = 0; nt < 4; ++nt) {
      const size_t ko = (size_t)(ki0 + nt * 16 + ln16) * DH + kg * 8;
      bf16x8 kb0 = ldb8(&kP[ko]);
      bf16x8 kb1 = ldb8(&kP[ko + 32]);
      const float ak = (xmask[b * TT + ki0 + nt * 16 + ln16] - 1.f) * MASKL;
      #pragma unroll
      for (int mt = 0; mt < 2; ++mt) {
        f32x4 dd = { aq[mt][0] + ak, aq[mt][1] + ak, aq[mt][2] + ak, aq[mt][3] + ak };
        dd = MFMA16(qa[mt][0], kb0, dd);
        dd = MFMA16(qa[mt][1], kb1, dd);
        #pragma unroll
        for (int jr = 0; jr < 4; ++jr) {
          const int qrow = mt * 16 + kg * 4 + jr;
          const int u = nt * 16 + ln16 - qrow + 31;
          rs[mt][jr] += exp2f(dd[jr] + b2f(G[w][qrow][u]));
        }
      }
    }
  }
  #pragma unroll
  for (int mt = 0; mt < 2; ++mt)
    #pragma unroll
    for (int jr = 0; jr < 4; ++jr) {
      float v = rs[mt][jr];
      v += __shfl_xor(v, 1); v += __shfl_xor(v, 2);
      v += __shfl_xor(v, 4); v += __shfl_xor(v, 8);
      rs[mt][jr] = v;
    }
  if (ln16 == 0) {
    #pragma unroll
    for (int mt = 0; mt < 2; ++mt)
      #pragma unroll
      for (int jr = 0; jr < 4; ++jr)
        red[w][mt * 16 + kg * 4 + jr] = rs[mt][jr];
  }
  __syncthreads();
  if (tid < 32)
    ls[(size_t)part * 32768 + (size_t)bh * TT + qi0 + tid] =
        red[0][tid] + red[1][tid] + red[2][tid] + red[3][tid];
}

// ---------- Pass 2 (MFMA): full-qi ctx; G in registers, P double-buffered ----------
// grid 512: bh=(bid&7)+8*((bid>>3)&3); t0=(bid>>5)*64. 16 serial qi chunks.
// Writes ctxS [b][t][512] directly (no partials, no reduce pass).
__global__ __launch_bounds__(256)
void ctx_mfma(const u16* __restrict__ qu, const u16* __restrict__ kk_,
              const u16* __restrict__ vv, const u16* __restrict__ pp,
              const float* __restrict__ corr, const float* __restrict__ xmask,
              u16* __restrict__ ctxS)
{
  const int tid = threadIdx.x;
  const int w = tid >> 6, lane = tid & 63;
  const int ln16 = lane & 15, kg = lane >> 4;
  const int l48 = lane & 48;
  const int bid = blockIdx.x;
  const int bh = (bid & 7) + 8 * ((bid >> 3) & 3);
  const int t0 = (bid >> 5) * 64;
  const int b = bh >> 3, h = bh & 7;
  const u16* quP = qu + (size_t)bh * TT * DH;
  const u16* kP  = kk_ + (size_t)bh * TT * DH;
  const u16* vP  = vv + (size_t)bh * DH * TT;
  const u16* pP  = pp + (size_t)h * 2048 * DH;
  const float* corrP = corr + (h << 11);

  __shared__ __align__(16) u16 P[2][64][72];   // double-buffered P[t][qi_local]

  bf16x8 ka[4][2];
  #pragma unroll
  for (int nt = 0; nt < 4; ++nt)
    #pragma unroll
    for (int kc = 0; kc < 2; ++kc)
      ka[nt][kc] = ldb8(&kP[(size_t)(t0 + nt * 16 + ln16) * DH + kc * 32 + kg * 8]);
  float at4[4];
  #pragma unroll
  for (int nt = 0; nt < 4; ++nt)
    at4[nt] = (xmask[b * TT + t0 + nt * 16 + ln16] - 1.f) * MASKL;

  // scores for chunk qcn -> P[buf]
  auto scores = [&](int qcn, int buf) {
    const int qw = qcn * 64 + w * 16;
    const int j0 = t0 - qw + 1008;
    const size_t qo = (size_t)(qw + ln16) * DH + kg * 8;
    bf16x8 qa0 = ldb8(&quP[qo]), qa1 = ldb8(&quP[qo + 32]);
    // pos bands in registers (incl corr)
    f32x4 g[5];
    #pragma unroll
    for (int n = 0; n < 5; ++n) {
      const size_t po = (size_t)(j0 + n * 16 + ln16) * DH + kg * 8;
      bf16x8 pb0 = ldb8(&pP[po]), pb1 = ldb8(&pP[po + 32]);
      const float cval = corrP[j0 + n * 16 + ln16];
      f32x4 t = {cval, cval, cval, cval};
      t = MFMA16(qa0, pb0, t);
      t = MFMA16(qa1, pb1, t);
      g[n] = t;
    }
    // gather prep: sg[jr][n] = G[qrow=kg*4+jr][*] shuffled to this lane's columns
    float sg[4][5];
    #pragma unroll
    for (int jr = 0; jr < 4; ++jr) {
      const int qrow = kg * 4 + jr;
      const int src = l48 | ((ln16 + 15 - qrow) & 15);
      #pragma unroll
      for (int n = 0; n < 5; ++n) sg[jr][n] = __shfl(g[n][jr], src);
    }
    float aqv[4];
    #pragma unroll
    for (int jr = 0; jr < 4; ++jr)
      aqv[jr] = (xmask[b * TT + qw + kg * 4 + jr] - 1.f) * MASKL;
    #pragma unroll
    for (int nt = 0; nt < 4; ++nt) {
      f32x4 dd = { aqv[0] + at4[nt], aqv[1] + at4[nt],
                   aqv[2] + at4[nt], aqv[3] + at4[nt] };
      dd = MFMA16(qa0, ka[nt][0], dd);
      dd = MFMA16(qa1, ka[nt][1], dd);
      float ev[4];
      #pragma unroll
      for (int jr = 0; jr < 4; ++jr) {
        const int qrow = kg * 4 + jr;
        const float val = (ln16 <= qrow) ? sg[jr][nt] : sg[jr][nt + 1];
        ev[jr] = exp2f(dd[jr] + val);
      }
      uint2 o2;
      o2.x = cvt2(ev[0], ev[1]);
      o2.y = cvt2(ev[2], ev[3]);
      *reinterpret_cast<uint2*>(&P[buf][nt * 16 + ln16][w * 16 + kg * 4]) = o2;
    }
  };

  f32x4 cacc[4] = {};
  scores(0, 0);
  __syncthreads();
  for (int i = 0; i < 16; ++i) {
    // PV from P[i&1]; overlaps with next chunk's scores below (no barrier between)
    const size_t vbase = (size_t)(w * 16 + ln16) * TT + i * 64 + kg * 8;
    bf16x8 vf0 = ldb8(&vP[vbase]), vf1 = ldb8(&vP[vbase + 32]);
    __builtin_amdgcn_s_setprio(1);
    #pragma unroll
    for (int nt = 0; nt < 4; ++nt) {
      bf16x8 pb0 = *reinterpret_cast<const bf16x8*>(&P[i & 1][nt * 16 + ln16][kg * 8]);
      bf16x8 pb1 = *reinterpret_cast<const bf16x8*>(&P[i & 1][nt * 16 + ln16][32 + kg * 8]);
      cacc[nt] = MFMA16(vf0, pb0, cacc[nt]);
      cacc[nt] = MFMA16(vf1, pb1, cacc[nt]);
    }
    __builtin_amdgcn_s_setprio(0);
    if (i < 15) {
      scores(i + 1, (i + 1) & 1);
      __syncthreads();
    }
  }
  #pragma unroll
  for (int nt = 0; nt < 4; ++nt) {
    const int t = t0 + nt * 16 + ln16;
    uint2 o2;
    o2.x = cvt2(cacc[nt][0], cacc[nt][1]);
    o2.y = cvt2(cacc[nt][2], cacc[nt][3]);
    *reinterpret_cast<uint2*>(
      &ctxS[((size_t)b * TT + t) * 512 + h * 64 + w * 16 + kg * 4]) = o2;
  }
}

// ---------- fold 1/l into v (in-place; vB fully rewritten every launch) ----------
__global__ __launch_bounds__(256)
void vscale(u16* __restrict__ vv, const float* __restrict__ ls)
{
  int i = blockIdx.x * 256 + threadIdx.x;     // 262144 groups of 8
  int bh = i >> 13;
  int rem = i & 8191;
  int d = rem >> 7;
  int qi0 = (rem & 127) * 8;
  const float* lsP = ls + bh * 1024 + qi0;
  u16* row = vv + ((size_t)bh * 64 + d) * 1024 + qi0;
  union { u16x8 v; u16 u[8]; } t;
  t.v = *(u16x8*)row;
  u16x8 o;
  #pragma unroll
  for (int e = 0; e < 8; ++e) {
    float linv = __builtin_amdgcn_rcpf(lsP[e] + lsP[32768 + e]);
    o[e] = f2b(b2f(t.u[e]) * linv);
  }
  *(u16x8*)row = o;
}

// ---------- launch ----------
extern "C" void kernel_launch(void* const* d_in, const int* in_sizes, int n_in,
                              void* d_out, int out_size, void* d_ws, size_t ws_size,
                              hipStream_t stream)
{
  (void)in_sizes; (void)n_in; (void)out_size;
  const float* x     = (const float*)d_in[0];
  const float* pe    = (const float*)d_in[1];
  const float* xm    = (const float*)d_in[2];
  const float* gamma = (const float*)d_in[3];
  const float* beta  = (const float*)d_in[4];
  const float* Wq    = (const float*)d_in[5];
  const float* bq    = (const float*)d_in[6];
  const float* Wk    = (const float*)d_in[7];
  const float* bk    = (const float*)d_in[8];
  const float* Wv    = (const float*)d_in[9];
  const float* bv    = (const float*)d_in[10];
  const float* Wp    = (const float*)d_in[11];
  const float* ub    = (const float*)d_in[12];
  const float* vb    = (const float*)d_in[13];
  const float* Wo    = (const float*)d_in[14];
  const float* bo    = (const float*)d_in[15];

  // workspace layout (bytes); ctxS lives in the staging region (xnT/posT/Wstk
  // are dead after proj_kernel) -- it must NOT alias quB, which ctx reads.
  char* ws = (char*)d_ws;
  u16*  quB  = (u16*) (ws + 0);          // [32][1024][64] bf16  (4 MiB)
  u16*  kB   = (u16*) (ws + 4194304);    // [32][1024][64] bf16  (4 MiB)
  u16*  vB   = (u16*) (ws + 8388608);    // [32][64][1024] bf16  (4 MiB)
  u16*  pB   = (u16*) (ws + 12582912);   // [8][2048][64] bf16   (2 MiB)
  float* corrB = (float*)(ws + 14680064);// [8][2048] f32        (64 KiB)
  float* lsB = (float*)(ws + 14745600);  // [2][32][1024] f32    (256 KiB)
  u16*  WoB  = (u16*) (ws + 15007744);   // [512][512] bf16      (512 KiB)
  u16*  ctxS = (u16*) (ws + 15532032);   // [4][1024][512] bf16  (4 MiB; overlays xnT)
  // staging (dead before ctxS is written) in the same region:
  u16*  xnT  = (u16*) (ws + 15532032);   // [4][1024][512] bf16  (4 MiB)
  u16*  posT = (u16*) (ws + 19726336);   // [2048][512] bf16     (2 MiB)
  u16*  Wstk = (u16*) (ws + 21823488);   // [2048][512] bf16     (2 MiB)
  float* wcorrB = (float*)(ws + 23920640); // [8][512] f32       (16 KiB)
  if (ws_size < 32309248) return;

  dim3 blk(256);

  prefix_kernel<<<dim3(1025), blk, 0, stream>>>(
      Wq, Wk, Wv, Wp, Wo, Wstk, WoB, pe, posT, x, gamma, beta, xnT, ub, vb, wcorrB);
  proj_kernel<<<dim3(1088), blk, 0, stream>>>(
      Wstk, xnT, posT, bq, ub, bk, bv, wcorrB, quB, kB, vB, pB, corrB);

  stats_mfma<<<dim3(2048), blk, 0, stream>>>(quB, kB, pB, corrB, xm, lsB);
  vscale<<<dim3(1024), blk, 0, stream>>>(vB, lsB);
  ctx_mfma<<<dim3(512), blk, 0, stream>>>(quB, kB, vB, pB, corrB, xm, ctxS);

  gemm2<512, 0><<<dim3(8, 8, 4), blk, 0, stream>>>(
      WoB, ctxS, (long)TT * CB, (long)CB * TT, TT, bo, (float*)d_out);
}

// Round 14
// 198.296 us; speedup vs baseline: 1.1554x; 1.0181x over previous
//
#include <hip/hip_runtime.h>
#include <hip/hip_bf16.h>
#include <cmath>

typedef unsigned short u16;
typedef __bf16 bf16_t;
typedef bf16_t bf16x8 __attribute__((ext_vector_type(8)));
typedef bf16_t bf16x2 __attribute__((ext_vector_type(2)));
typedef float f32x4 __attribute__((ext_vector_type(4)));
typedef u16 u16x8 __attribute__((ext_vector_type(8)));

#define MFMA16(A,B,C) __builtin_amdgcn_mfma_f32_16x16x32_bf16(A,B,C,0,0,0)

#define CB 512
#define TT 1024
#define NH 8
#define DH 64
// ALPHA = (1/sqrt(512)) * log2(e): folded into qu and corr so exp(score)=exp2(s2)
#define ALPHA (0.044194173824159216f * 1.4426950408889634f)
#define MASKL 14426.950408889634f   // 10000 * log2(e)

// native bf16 convert (RNE; compiler emits v_cvt_pk_bf16_f32)
static __device__ __forceinline__ u16 f2b(float f) {
  union { bf16_t b; u16 u; } r; r.b = (bf16_t)f; return r.u;
}
static __device__ __forceinline__ unsigned cvt2(float lo, float hi) {
  union { bf16x2 v; unsigned u; } r;
  r.v[0] = (bf16_t)lo; r.v[1] = (bf16_t)hi; return r.u;
}
static __device__ __forceinline__ float b2f(u16 u) {
  return __uint_as_float(((unsigned)u) << 16);
}
static __device__ __forceinline__ bf16x8 ldb8(const u16* p) {
  return *reinterpret_cast<const bf16x8*>(p);
}

// ========== merged prefix: convert5 (640) | transpose_pe (256) | ln (128) | wcorr (1) ==========
__global__ __launch_bounds__(256)
void prefix_kernel(const float* __restrict__ Wq, const float* __restrict__ Wk,
                   const float* __restrict__ Wv, const float* __restrict__ Wp,
                   const float* __restrict__ Wo,
                   u16* __restrict__ Wstk, u16* __restrict__ WoB,
                   const float* __restrict__ pe, u16* __restrict__ posT,
                   const float* __restrict__ x, const float* __restrict__ gamma,
                   const float* __restrict__ beta, u16* __restrict__ xnT,
                   const float* __restrict__ ub, const float* __restrict__ vb,
                   float* __restrict__ wcorr)
{
  __shared__ float tile[64][65];                 // transpose; ln/wcorr reuse slices
  const int bid = blockIdx.x;
  const int tid = threadIdx.x;
  if (bid < 640) {
    int i = bid * 256 + tid;
    int sel = i >> 15, loc = i & 32767;
    const float* src = (sel == 0) ? Wq : (sel == 1) ? Wk : (sel == 2) ? Wv
                     : (sel == 3) ? Wp : Wo;
    const float4 a = ((const float4*)src)[loc * 2 + 0];
    const float4 b = ((const float4*)src)[loc * 2 + 1];
    u16x8 o;
    o[0] = f2b(a.x); o[1] = f2b(a.y); o[2] = f2b(a.z); o[3] = f2b(a.w);
    o[4] = f2b(b.x); o[5] = f2b(b.y); o[6] = f2b(b.z); o[7] = f2b(b.w);
    u16* dst = (sel < 4) ? (Wstk + (size_t)i * 8) : (WoB + (size_t)loc * 8);
    *(u16x8*)dst = o;
  } else if (bid < 896) {
    int bb = bid - 640;
    int j0 = (bb & 31) * 64, c0 = (bb >> 5) * 64;
    for (int e = tid; e < 4096; e += 256) {
      int cc = e >> 6, jj = e & 63;
      int j = j0 + jj;
      tile[jj][cc] = (j < 2047) ? pe[(size_t)(c0 + cc) * 2047 + j] : 0.f;
    }
    __syncthreads();
    for (int e = tid; e < 4096; e += 256) {
      int jj = e >> 6, cc = e & 63;
      posT[(size_t)(j0 + jj) * 512 + c0 + cc] = f2b(tile[jj][cc]);
    }
  } else if (bid < 1024) {
    float (*sred)[33]  = (float(*)[33])&tile[0][0];
    float (*ssred)[33] = (float(*)[33])&tile[8][0];
    int bb = bid - 896;
    int tl = tid & 31, cg = tid >> 5;
    int t = (bb & 31) * 32 + tl;
    int b = bb >> 5;
    const float* xb = x + (size_t)b * CB * TT + t;
    float s = 0.f, ss = 0.f;
    for (int c = cg * 64; c < cg * 64 + 64; ++c) {
      float v = xb[(size_t)c * TT];
      s += v; ss += v * v;
    }
    sred[cg][tl] = s; ssred[cg][tl] = ss;
    __syncthreads();
    float S = 0.f, SS = 0.f;
    #pragma unroll
    for (int g = 0; g < 8; ++g) { S += sred[g][tl]; SS += ssred[g][tl]; }
    float mean = S * (1.f / 512.f);
    float var = SS * (1.f / 512.f) - mean * mean;
    float rstd = rsqrtf(var + 1e-5f);
    u16* orow = xnT + ((size_t)b * TT + t) * CB;
    for (int c8 = 0; c8 < 8; ++c8) {
      int c = cg * 64 + c8 * 8;
      u16x8 o;
      #pragma unroll
      for (int j = 0; j < 8; ++j) {
        float v = xb[(size_t)(c + j) * TT];
        o[j] = f2b((v - mean) * rstd * gamma[c + j] + beta[c + j]);
      }
      *(u16x8*)(orow + c) = o;
    }
  } else {
    // wcorr[h][c] = sum_d (vb-ub)[h][d] * Wp[h*64+d][c]
    float* dl2 = &tile[0][0];                  // 512 floats
    for (int i = tid; i < 512; i += 256) dl2[i] = vb[i] - ub[i];
    __syncthreads();
    const int hh = tid >> 5;
    const int c0 = (tid & 31) * 16;
    float acc[16] = {};
    for (int d = 0; d < 64; ++d) {
      const float dv = dl2[hh * 64 + d];
      const float* wrow = Wp + (size_t)(hh * 64 + d) * 512 + c0;
      #pragma unroll
      for (int j = 0; j < 16; ++j) acc[j] += dv * wrow[j];
    }
    #pragma unroll
    for (int j = 0; j < 16; ++j) wcorr[hh * 512 + c0 + j] = acc[j];
  }
}

// ========== merged projections: q/k/v (768) | p (256) | corr (64) ==========
__global__ __launch_bounds__(256)
void proj_kernel(const u16* __restrict__ Wstk, const u16* __restrict__ xnT,
                 const u16* __restrict__ posT,
                 const float* __restrict__ bq, const float* __restrict__ ub,
                 const float* __restrict__ bk, const float* __restrict__ bv,
                 const float* __restrict__ wcorr,
                 u16* __restrict__ quB, u16* __restrict__ kB, u16* __restrict__ vB,
                 u16* __restrict__ pB, float* __restrict__ corrOut)
{
  __shared__ float wc[512];
  const int bid = blockIdx.x;
  const int tid = threadIdx.x, w = tid >> 6, lane = tid & 63;
  const int ln16 = lane & 15, kg = lane >> 4;
  if (bid < 768) {
    const int bx = bid & 7;
    const int t = bid >> 3;
    const int my = t % 24;
    const int z = t / 24;
    const int wm = w & 1, wn = w >> 1;
    const int sec = my >> 3;
    const int m0l = (my & 7) * 64 + wm * 32;
    const int n0 = bx * 128 + wn * 64;
    const long XS = (long)TT * CB;
    const long QS = (long)NH * TT * DH;
    const u16* Ar = Wstk + (size_t)(sec * 512 + m0l + ln16) * 512 + kg * 8;
    const u16* Br = xnT + (size_t)z * XS + (size_t)(n0 + ln16) * 512 + kg * 8;
    f32x4 acc[2][4] = {};
    #pragma unroll 2
    for (int ks = 0; ks < 16; ++ks) {
      bf16x8 a[2], bb[4];
      #pragma unroll
      for (int mt = 0; mt < 2; ++mt) a[mt] = ldb8(Ar + (size_t)mt * 16 * 512 + ks * 32);
      #pragma unroll
      for (int nt = 0; nt < 4; ++nt) bb[nt] = ldb8(Br + (size_t)nt * 16 * 512 + ks * 32);
      #pragma unroll
      for (int mt = 0; mt < 2; ++mt)
        #pragma unroll
        for (int nt = 0; nt < 4; ++nt)
          acc[mt][nt] = MFMA16(a[mt], bb[nt], acc[mt][nt]);
    }
    const float scl = (sec == 0) ? ALPHA : 1.f;
    float add[2][4];
    #pragma unroll
    for (int mt = 0; mt < 2; ++mt)
      #pragma unroll
      for (int jr = 0; jr < 4; ++jr) {
        int m = m0l + mt * 16 + kg * 4 + jr;
        add[mt][jr] = (sec == 0) ? (bq[m] + ub[m]) : (sec == 1) ? bk[m] : bv[m];
      }
    if (sec < 2) {
      u16* dst = sec ? kB : quB;
      #pragma unroll
      for (int mt = 0; mt < 2; ++mt)
        #pragma unroll
        for (int nt = 0; nt < 4; ++nt) {
          const int n = n0 + nt * 16 + ln16;
          const int m_low = m0l + mt * 16;
          const size_t o = (size_t)z * QS +
                           ((size_t)(m_low >> 6) * TT + n) * 64 + (m_low & 63) + kg * 4;
          uint2 o2;
          o2.x = cvt2((acc[mt][nt][0] + add[mt][0]) * scl,
                      (acc[mt][nt][1] + add[mt][1]) * scl);
          o2.y = cvt2((acc[mt][nt][2] + add[mt][2]) * scl,
                      (acc[mt][nt][3] + add[mt][3]) * scl);
          *reinterpret_cast<uint2*>(dst + o) = o2;
        }
    } else {
      #pragma unroll
      for (int mt = 0; mt < 2; ++mt)
        #pragma unroll
        for (int nt = 0; nt < 4; ++nt) {
          const int n = n0 + nt * 16 + ln16;
          #pragma unroll
          for (int jr = 0; jr < 4; ++jr)
            vB[(size_t)z * QS + (size_t)(m0l + mt * 16 + kg * 4 + jr) * TT + n] =
                f2b(acc[mt][nt][jr] + add[mt][jr]);
        }
    }
  } else if (bid < 1024) {
    // p projection: pB[h][2048][64] (OMODE-1 layout, no bias)
    const int i = bid - 768;
    const int m0 = (i >> 5) * 64 + (w & 1) * 32;
    const int n0 = (i & 31) * 64 + (w >> 1) * 32;
    const u16* Ar = Wstk + (size_t)(1536 + m0 + ln16) * 512 + kg * 8;
    const u16* Br = posT + (size_t)(n0 + ln16) * 512 + kg * 8;
    f32x4 acc[2][2] = {};
    #pragma unroll 2
    for (int ks = 0; ks < 16; ++ks) {
      bf16x8 a[2], bb[2];
      #pragma unroll
      for (int mt = 0; mt < 2; ++mt) a[mt] = ldb8(Ar + (size_t)mt * 16 * 512 + ks * 32);
      #pragma unroll
      for (int nt = 0; nt < 2; ++nt) bb[nt] = ldb8(Br + (size_t)nt * 16 * 512 + ks * 32);
      #pragma unroll
      for (int mt = 0; mt < 2; ++mt)
        #pragma unroll
        for (int nt = 0; nt < 2; ++nt)
          acc[mt][nt] = MFMA16(a[mt], bb[nt], acc[mt][nt]);
    }
    #pragma unroll
    for (int mt = 0; mt < 2; ++mt)
      #pragma unroll
      for (int nt = 0; nt < 2; ++nt) {
        const int n = n0 + nt * 16 + ln16;
        const int m_low = m0 + mt * 16;
        const size_t o = ((size_t)(m_low >> 6) * 2048 + n) * 64 + (m_low & 63) + kg * 4;
        uint2 o2;
        o2.x = cvt2(acc[mt][nt][0], acc[mt][nt][1]);
        o2.y = cvt2(acc[mt][nt][2], acc[mt][nt][3]);
        *reinterpret_cast<uint2*>(pB + o) = o2;
      }
  } else {
    // corr[h][j] = ALPHA * sum_c wcorr[h][c] * posT[j][c]
    const int i = bid - 1024;
    const int hh = i >> 3;
    const int j = (i & 7) * 256 + tid;
    for (int c = tid; c < 512; c += 256) wc[c] = wcorr[hh * 512 + c];
    __syncthreads();
    const u16* prow = posT + (size_t)j * 512;
    float s = 0.f;
    #pragma unroll 4
    for (int c8 = 0; c8 < 64; ++c8) {
      union { bf16x8 v; u16 u[8]; } pu;
      pu.v = ldb8(prow + c8 * 8);
      #pragma unroll
      for (int e = 0; e < 8; ++e) s += b2f(pu.u[e]) * wc[c8 * 8 + e];
    }
    corrOut[hh * 2048 + j] = s * ALPHA;
  }
}

// ---------- gemm2: wave 32m x 64n, block 64m x 128n (out projection) ----------
template<int K, int OMODE>
__global__ __launch_bounds__(256)
void gemm2(const u16* __restrict__ A, const u16* __restrict__ XT,
           long xStride, long oStride, int Nout,
           const float* __restrict__ b0, void* __restrict__ outv)
{
  const int tid = threadIdx.x, w = tid >> 6, lane = tid & 63;
  const int ln16 = lane & 15, kg = lane >> 4;
  const int wm = w & 1, wn = w >> 1;
  const int m0 = blockIdx.y * 64 + wm * 32;
  const int n0 = blockIdx.x * 128 + wn * 64;
  const int z = blockIdx.z;
  const u16* Ar = A + (size_t)(m0 + ln16) * K + kg * 8;
  const u16* Br = XT + (size_t)z * xStride + (size_t)(n0 + ln16) * K + kg * 8;
  f32x4 acc[2][4] = {};
  #pragma unroll 2
  for (int ks = 0; ks < K / 32; ++ks) {
    bf16x8 a[2], bb[4];
    #pragma unroll
    for (int mt = 0; mt < 2; ++mt) a[mt] = ldb8(Ar + (size_t)mt * 16 * K + ks * 32);
    #pragma unroll
    for (int nt = 0; nt < 4; ++nt) bb[nt] = ldb8(Br + (size_t)nt * 16 * K + ks * 32);
    #pragma unroll
    for (int mt = 0; mt < 2; ++mt)
      #pragma unroll
      for (int nt = 0; nt < 4; ++nt)
        acc[mt][nt] = MFMA16(a[mt], bb[nt], acc[mt][nt]);
  }
  float add[2][4];
  #pragma unroll
  for (int mt = 0; mt < 2; ++mt)
    #pragma unroll
    for (int jr = 0; jr < 4; ++jr)
      add[mt][jr] = b0 ? b0[m0 + mt * 16 + kg * 4 + jr] : 0.f;
  #pragma unroll
  for (int mt = 0; mt < 2; ++mt)
    #pragma unroll
    for (int nt = 0; nt < 4; ++nt) {
      const int n = n0 + nt * 16 + ln16;
      if constexpr (OMODE == 0) {
        float* out = (float*)outv;
        #pragma unroll
        for (int jr = 0; jr < 4; ++jr)
          out[(size_t)z * oStride + (size_t)(m0 + mt * 16 + kg * 4 + jr) * Nout + n] =
              acc[mt][nt][jr] + add[mt][jr];
      } else {
        const int m_low = m0 + mt * 16;
        const size_t o = (size_t)z * oStride +
                         ((size_t)(m_low >> 6) * Nout + n) * 64 + (m_low & 63) + kg * 4;
        uint2 o2;
        o2.x = cvt2(acc[mt][nt][0] + add[mt][0], acc[mt][nt][1] + add[mt][1]);
        o2.y = cvt2(acc[mt][nt][2] + add[mt][2], acc[mt][nt][3] + add[mt][3]);
        *reinterpret_cast<uint2*>((u16*)outv + o) = o2;
      }
    }
}

// ---------- Pass 1 (MFMA): partial l over a ki half (LDS G band) ----------
__global__ __launch_bounds__(256)
void stats_mfma(const u16* __restrict__ qu, const u16* __restrict__ kk_,
                const u16* __restrict__ pp, const float* __restrict__ corr,
                const float* __restrict__ xmask, float* __restrict__ ls)
{
  const int tid = threadIdx.x;
  const int w = tid >> 6, lane = tid & 63;
  const int ln16 = lane & 15, kg = lane >> 4;
  const int bid = blockIdx.x;
  const int bh = (bid & 7) + 8 * ((bid >> 3) & 3);
  const int rest = bid >> 5;
  const int qi0 = (rest & 31) * 32;
  const int part = rest >> 5;
  const int b = bh >> 3, h = bh & 7;
  const u16* quP = qu + (size_t)bh * TT * DH;
  const u16* kP  = kk_ + (size_t)bh * TT * DH;
  const u16* pP  = pp + (size_t)h * 2048 * DH;
  const float* corrP = corr + (h << 11);

  __shared__ u16 G[4][32][100];
  __shared__ float red[4][32];

  bf16x8 qa[2][2];
  #pragma unroll
  for (int mt = 0; mt < 2; ++mt)
    #pragma unroll
    for (int kc = 0; kc < 2; ++kc)
      qa[mt][kc] = ldb8(&quP[(size_t)(qi0 + mt * 16 + ln16) * DH + kc * 32 + kg * 8]);
  float aq[2][4];
  #pragma unroll
  for (int mt = 0; mt < 2; ++mt)
    #pragma unroll
    for (int jr = 0; jr < 4; ++jr)
      aq[mt][jr] = (xmask[b * TT + qi0 + mt * 16 + kg * 4 + jr] - 1.f) * MASKL;

  float rs[2][4] = {};
  for (int c = 0; c < 2; ++c) {
    const int ki0 = (part * 8 + c * 4 + w) * 64;
    const int j0 = ki0 - qi0 + 992;
    #pragma unroll
    for (int nt = 0; nt < 6; ++nt) {
      const size_t po = (size_t)(j0 + nt * 16 + ln16) * DH + kg * 8;
      bf16x8 pb0 = ldb8(&pP[po]);
      bf16x8 pb1 = ldb8(&pP[po + 32]);
      const float cval = corrP[j0 + nt * 16 + ln16];
      #pragma unroll
      for (int mt = 0; mt < 2; ++mt) {
        f32x4 g = {0.f, 0.f, 0.f, 0.f};
        g = MFMA16(qa[mt][0], pb0, g);
        g = MFMA16(qa[mt][1], pb1, g);
        #pragma unroll
        for (int jr = 0; jr < 4; ++jr)
          G[w][mt * 16 + kg * 4 + jr][nt * 16 + ln16] = f2b(g[jr] + cval);
      }
    }
    #pragma unroll
    for (int nt = 0; nt < 4; ++nt) {
      const size_t ko = (size_t)(ki0 + nt * 16 + ln16) * DH + kg * 8;
      bf16x8 kb0 = ldb8(&kP[ko]);
      bf16x8 kb1 = ldb8(&kP[ko + 32]);
      const float ak = (xmask[b * TT + ki0 + nt * 16 + ln16] - 1.f) * MASKL;
      #pragma unroll
      for (int mt = 0; mt < 2; ++mt) {
        f32x4 dd = { aq[mt][0] + ak, aq[mt][1] + ak, aq[mt][2] + ak, aq[mt][3] + ak };
        dd = MFMA16(qa[mt][0], kb0, dd);
        dd = MFMA16(qa[mt][1], kb1, dd);
        #pragma unroll
        for (int jr = 0; jr < 4; ++jr) {
          const int qrow = mt * 16 + kg * 4 + jr;
          const int u = nt * 16 + ln16 - qrow + 31;
          rs[mt][jr] += exp2f(dd[jr] + b2f(G[w][qrow][u]));
        }
      }
    }
  }
  #pragma unroll
  for (int mt = 0; mt < 2; ++mt)
    #pragma unroll
    for (int jr = 0; jr < 4; ++jr) {
      float v = rs[mt][jr];
      v += __shfl_xor(v, 1); v += __shfl_xor(v, 2);
      v += __shfl_xor(v, 4); v += __shfl_xor(v, 8);
      rs[mt][jr] = v;
    }
  if (ln16 == 0) {
    #pragma unroll
    for (int mt = 0; mt < 2; ++mt)
      #pragma unroll
      for (int jr = 0; jr < 4; ++jr)
        red[w][mt * 16 + kg * 4 + jr] = rs[mt][jr];
  }
  __syncthreads();
  if (tid < 32)
    ls[(size_t)part * 32768 + (size_t)bh * TT + qi0 + tid] =
        red[0][tid] + red[1][tid] + red[2][tid] + red[3][tid];
}

// ---------- Pass 2 (MFMA): full-qi ctx; G in registers, P double-buffered ----------
// grid 512: bh=(bid&7)+8*((bid>>3)&3); t0=(bid>>5)*64. 16 serial qi chunks.
// 1/l folded into P (no separate vscale pass). Writes ctxS [b][t][512] directly.
__global__ __launch_bounds__(256)
void ctx_mfma(const u16* __restrict__ qu, const u16* __restrict__ kk_,
              const u16* __restrict__ vv, const u16* __restrict__ pp,
              const float* __restrict__ corr, const float* __restrict__ xmask,
              const float* __restrict__ ls, u16* __restrict__ ctxS)
{
  const int tid = threadIdx.x;
  const int w = tid >> 6, lane = tid & 63;
  const int ln16 = lane & 15, kg = lane >> 4;
  const int l48 = lane & 48;
  const int bid = blockIdx.x;
  const int bh = (bid & 7) + 8 * ((bid >> 3) & 3);
  const int t0 = (bid >> 5) * 64;
  const int b = bh >> 3, h = bh & 7;
  const u16* quP = qu + (size_t)bh * TT * DH;
  const u16* kP  = kk_ + (size_t)bh * TT * DH;
  const u16* vP  = vv + (size_t)bh * DH * TT;
  const u16* pP  = pp + (size_t)h * 2048 * DH;
  const float* corrP = corr + (h << 11);
  const float* lsP = ls + (size_t)bh * TT;

  __shared__ __align__(16) u16 P[2][64][72];   // double-buffered P[t][qi_local]

  bf16x8 ka[4][2];
  #pragma unroll
  for (int nt = 0; nt < 4; ++nt)
    #pragma unroll
    for (int kc = 0; kc < 2; ++kc)
      ka[nt][kc] = ldb8(&kP[(size_t)(t0 + nt * 16 + ln16) * DH + kc * 32 + kg * 8]);
  float at4[4];
  #pragma unroll
  for (int nt = 0; nt < 4; ++nt)
    at4[nt] = (xmask[b * TT + t0 + nt * 16 + ln16] - 1.f) * MASKL;

  // scores for chunk qcn -> P[buf]
  auto scores = [&](int qcn, int buf) {
    const int qw = qcn * 64 + w * 16;
    const int j0 = t0 - qw + 1008;
    const size_t qo = (size_t)(qw + ln16) * DH + kg * 8;
    bf16x8 qa0 = ldb8(&quP[qo]), qa1 = ldb8(&quP[qo + 32]);
    // pos bands in registers (incl corr)
    f32x4 g[5];
    #pragma unroll
    for (int n = 0; n < 5; ++n) {
      const size_t po = (size_t)(j0 + n * 16 + ln16) * DH + kg * 8;
      bf16x8 pb0 = ldb8(&pP[po]), pb1 = ldb8(&pP[po + 32]);
      const float cval = corrP[j0 + n * 16 + ln16];
      f32x4 t = {cval, cval, cval, cval};
      t = MFMA16(qa0, pb0, t);
      t = MFMA16(qa1, pb1, t);
      g[n] = t;
    }
    // gather prep: sg[jr][n] = G[qrow=kg*4+jr][*] shuffled to this lane's columns
    float sg[4][5];
    #pragma unroll
    for (int jr = 0; jr < 4; ++jr) {
      const int qrow = kg * 4 + jr;
      const int src = l48 | ((ln16 + 15 - qrow) & 15);
      #pragma unroll
      for (int n = 0; n < 5; ++n) sg[jr][n] = __shfl(g[n][jr], src);
    }
    float aqv[4], linv[4];
    #pragma unroll
    for (int jr = 0; jr < 4; ++jr) {
      const int qi = qw + kg * 4 + jr;
      aqv[jr] = (xmask[b * TT + qi] - 1.f) * MASKL;
      linv[jr] = __builtin_amdgcn_rcpf(lsP[qi] + lsP[32768 + qi]);
    }
    #pragma unroll
    for (int nt = 0; nt < 4; ++nt) {
      f32x4 dd = { aqv[0] + at4[nt], aqv[1] + at4[nt],
                   aqv[2] + at4[nt], aqv[3] + at4[nt] };
      dd = MFMA16(qa0, ka[nt][0], dd);
      dd = MFMA16(qa1, ka[nt][1], dd);
      float ev[4];
      #pragma unroll
      for (int jr = 0; jr < 4; ++jr) {
        const int qrow = kg * 4 + jr;
        const float val = (ln16 <= qrow) ? sg[jr][nt] : sg[jr][nt + 1];
        ev[jr] = exp2f(dd[jr] + val) * linv[jr];
      }
      uint2 o2;
      o2.x = cvt2(ev[0], ev[1]);
      o2.y = cvt2(ev[2], ev[3]);
      *reinterpret_cast<uint2*>(&P[buf][nt * 16 + ln16][w * 16 + kg * 4]) = o2;
    }
  };

  f32x4 cacc[4] = {};
  scores(0, 0);
  __syncthreads();
  for (int i = 0; i < 16; ++i) {
    // PV from P[i&1]; overlaps with next chunk's scores below (no barrier between)
    const size_t vbase = (size_t)(w * 16 + ln16) * TT + i * 64 + kg * 8;
    bf16x8 vf0 = ldb8(&vP[vbase]), vf1 = ldb8(&vP[vbase + 32]);
    __builtin_amdgcn_s_setprio(1);
    #pragma unroll
    for (int nt = 0; nt < 4; ++nt) {
      bf16x8 pb0 = *reinterpret_cast<const bf16x8*>(&P[i & 1][nt * 16 + ln16][kg * 8]);
      bf16x8 pb1 = *reinterpret_cast<const bf16x8*>(&P[i & 1][nt * 16 + ln16][32 + kg * 8]);
      cacc[nt] = MFMA16(vf0, pb0, cacc[nt]);
      cacc[nt] = MFMA16(vf1, pb1, cacc[nt]);
    }
    __builtin_amdgcn_s_setprio(0);
    if (i < 15) {
      scores(i + 1, (i + 1) & 1);
      __syncthreads();
    }
  }
  #pragma unroll
  for (int nt = 0; nt < 4; ++nt) {
    const int t = t0 + nt * 16 + ln16;
    uint2 o2;
    o2.x = cvt2(cacc[nt][0], cacc[nt][1]);
    o2.y = cvt2(cacc[nt][2], cacc[nt][3]);
    *reinterpret_cast<uint2*>(
      &ctxS[((size_t)b * TT + t) * 512 + h * 64 + w * 16 + kg * 4]) = o2;
  }
}

// ---------- launch ----------
extern "C" void kernel_launch(void* const* d_in, const int* in_sizes, int n_in,
                              void* d_out, int out_size, void* d_ws, size_t ws_size,
                              hipStream_t stream)
{
  (void)in_sizes; (void)n_in; (void)out_size;
  const float* x     = (const float*)d_in[0];
  const float* pe    = (const float*)d_in[1];
  const float* xm    = (const float*)d_in[2];
  const float* gamma = (const float*)d_in[3];
  const float* beta  = (const float*)d_in[4];
  const float* Wq    = (const float*)d_in[5];
  const float* bq    = (const float*)d_in[6];
  const float* Wk    = (const float*)d_in[7];
  const float* bk    = (const float*)d_in[8];
  const float* Wv    = (const float*)d_in[9];
  const float* bv    = (const float*)d_in[10];
  const float* Wp    = (const float*)d_in[11];
  const float* ub    = (const float*)d_in[12];
  const float* vb    = (const float*)d_in[13];
  const float* Wo    = (const float*)d_in[14];
  const float* bo    = (const float*)d_in[15];

  // workspace layout (bytes); ctxS lives in the staging region (xnT/posT/Wstk
  // are dead after proj_kernel) -- it must NOT alias quB, which ctx reads.
  char* ws = (char*)d_ws;
  u16*  quB  = (u16*) (ws + 0);          // [32][1024][64] bf16  (4 MiB)
  u16*  kB   = (u16*) (ws + 4194304);    // [32][1024][64] bf16  (4 MiB)
  u16*  vB   = (u16*) (ws + 8388608);    // [32][64][1024] bf16  (4 MiB)
  u16*  pB   = (u16*) (ws + 12582912);   // [8][2048][64] bf16   (2 MiB)
  float* corrB = (float*)(ws + 14680064);// [8][2048] f32        (64 KiB)
  float* lsB = (float*)(ws + 14745600);  // [2][32][1024] f32    (256 KiB)
  u16*  WoB  = (u16*) (ws + 15007744);   // [512][512] bf16      (512 KiB)
  u16*  ctxS = (u16*) (ws + 15532032);   // [4][1024][512] bf16  (4 MiB; overlays xnT)
  // staging (dead before ctxS is written) in the same region:
  u16*  xnT  = (u16*) (ws + 15532032);   // [4][1024][512] bf16  (4 MiB)
  u16*  posT = (u16*) (ws + 19726336);   // [2048][512] bf16     (2 MiB)
  u16*  Wstk = (u16*) (ws + 21823488);   // [2048][512] bf16     (2 MiB)
  float* wcorrB = (float*)(ws + 23920640); // [8][512] f32       (16 KiB)
  if (ws_size < 32309248) return;

  dim3 blk(256);

  prefix_kernel<<<dim3(1025), blk, 0, stream>>>(
      Wq, Wk, Wv, Wp, Wo, Wstk, WoB, pe, posT, x, gamma, beta, xnT, ub, vb, wcorrB);
  proj_kernel<<<dim3(1088), blk, 0, stream>>>(
      Wstk, xnT, posT, bq, ub, bk, bv, wcorrB, quB, kB, vB, pB, corrB);

  stats_mfma<<<dim3(2048), blk, 0, stream>>>(quB, kB, pB, corrB, xm, lsB);
  ctx_mfma<<<dim3(512), blk, 0, stream>>>(quB, kB, vB, pB, corrB, xm, lsB, ctxS);

  gemm2<512, 0><<<dim3(8, 8, 4), blk, 0, stream>>>(
      WoB, ctxS, (long)TT * CB, (long)CB * TT, TT, bo, (float*)d_out);
}

// Round 15
// 197.407 us; speedup vs baseline: 1.1606x; 1.0045x over previous
//
#include <hip/hip_runtime.h>
#include <hip/hip_bf16.h>
#include <cmath>

typedef unsigned short u16;
typedef __bf16 bf16_t;
typedef bf16_t bf16x8 __attribute__((ext_vector_type(8)));
typedef bf16_t bf16x2 __attribute__((ext_vector_type(2)));
typedef float f32x4 __attribute__((ext_vector_type(4)));
typedef u16 u16x8 __attribute__((ext_vector_type(8)));

#define MFMA16(A,B,C) __builtin_amdgcn_mfma_f32_16x16x32_bf16(A,B,C,0,0,0)

#define CB 512
#define TT 1024
#define NH 8
#define DH 64
// ALPHA = (1/sqrt(512)) * log2(e): folded into qu and corr so exp(score)=exp2(s2)
#define ALPHA (0.044194173824159216f * 1.4426950408889634f)
#define MASKL 14426.950408889634f   // 10000 * log2(e)

// native bf16 convert (RNE; compiler emits v_cvt_pk_bf16_f32)
static __device__ __forceinline__ u16 f2b(float f) {
  union { bf16_t b; u16 u; } r; r.b = (bf16_t)f; return r.u;
}
static __device__ __forceinline__ unsigned cvt2(float lo, float hi) {
  union { bf16x2 v; unsigned u; } r;
  r.v[0] = (bf16_t)lo; r.v[1] = (bf16_t)hi; return r.u;
}
static __device__ __forceinline__ float b2f(u16 u) {
  return __uint_as_float(((unsigned)u) << 16);
}
static __device__ __forceinline__ bf16x8 ldb8(const u16* p) {
  return *reinterpret_cast<const bf16x8*>(p);
}

// ========== merged prefix: convert5 (640) | transpose_pe (256) | ln (128) | wcorr (1) ==========
__global__ __launch_bounds__(256)
void prefix_kernel(const float* __restrict__ Wq, const float* __restrict__ Wk,
                   const float* __restrict__ Wv, const float* __restrict__ Wp,
                   const float* __restrict__ Wo,
                   u16* __restrict__ Wstk, u16* __restrict__ WoB,
                   const float* __restrict__ pe, u16* __restrict__ posT,
                   const float* __restrict__ x, const float* __restrict__ gamma,
                   const float* __restrict__ beta, u16* __restrict__ xnT,
                   const float* __restrict__ ub, const float* __restrict__ vb,
                   float* __restrict__ wcorr)
{
  __shared__ float tile[64][65];                 // transpose; ln/wcorr reuse slices
  const int bid = blockIdx.x;
  const int tid = threadIdx.x;
  if (bid < 640) {
    int i = bid * 256 + tid;
    int sel = i >> 15, loc = i & 32767;
    const float* src = (sel == 0) ? Wq : (sel == 1) ? Wk : (sel == 2) ? Wv
                     : (sel == 3) ? Wp : Wo;
    const float4 a = ((const float4*)src)[loc * 2 + 0];
    const float4 b = ((const float4*)src)[loc * 2 + 1];
    u16x8 o;
    o[0] = f2b(a.x); o[1] = f2b(a.y); o[2] = f2b(a.z); o[3] = f2b(a.w);
    o[4] = f2b(b.x); o[5] = f2b(b.y); o[6] = f2b(b.z); o[7] = f2b(b.w);
    u16* dst = (sel < 4) ? (Wstk + (size_t)i * 8) : (WoB + (size_t)loc * 8);
    *(u16x8*)dst = o;
  } else if (bid < 896) {
    int bb = bid - 640;
    int j0 = (bb & 31) * 64, c0 = (bb >> 5) * 64;
    for (int e = tid; e < 4096; e += 256) {
      int cc = e >> 6, jj = e & 63;
      int j = j0 + jj;
      tile[jj][cc] = (j < 2047) ? pe[(size_t)(c0 + cc) * 2047 + j] : 0.f;
    }
    __syncthreads();
    for (int e = tid; e < 4096; e += 256) {
      int jj = e >> 6, cc = e & 63;
      posT[(size_t)(j0 + jj) * 512 + c0 + cc] = f2b(tile[jj][cc]);
    }
  } else if (bid < 1024) {
    float (*sred)[33]  = (float(*)[33])&tile[0][0];
    float (*ssred)[33] = (float(*)[33])&tile[8][0];
    int bb = bid - 896;
    int tl = tid & 31, cg = tid >> 5;
    int t = (bb & 31) * 32 + tl;
    int b = bb >> 5;
    const float* xb = x + (size_t)b * CB * TT + t;
    float s = 0.f, ss = 0.f;
    for (int c = cg * 64; c < cg * 64 + 64; ++c) {
      float v = xb[(size_t)c * TT];
      s += v; ss += v * v;
    }
    sred[cg][tl] = s; ssred[cg][tl] = ss;
    __syncthreads();
    float S = 0.f, SS = 0.f;
    #pragma unroll
    for (int g = 0; g < 8; ++g) { S += sred[g][tl]; SS += ssred[g][tl]; }
    float mean = S * (1.f / 512.f);
    float var = SS * (1.f / 512.f) - mean * mean;
    float rstd = rsqrtf(var + 1e-5f);
    u16* orow = xnT + ((size_t)b * TT + t) * CB;
    for (int c8 = 0; c8 < 8; ++c8) {
      int c = cg * 64 + c8 * 8;
      u16x8 o;
      #pragma unroll
      for (int j = 0; j < 8; ++j) {
        float v = xb[(size_t)(c + j) * TT];
        o[j] = f2b((v - mean) * rstd * gamma[c + j] + beta[c + j]);
      }
      *(u16x8*)(orow + c) = o;
    }
  } else {
    // wcorr[h][c] = sum_d (vb-ub)[h][d] * Wp[h*64+d][c]
    float* dl2 = &tile[0][0];                  // 512 floats
    for (int i = tid; i < 512; i += 256) dl2[i] = vb[i] - ub[i];
    __syncthreads();
    const int hh = tid >> 5;
    const int c0 = (tid & 31) * 16;
    float acc[16] = {};
    for (int d = 0; d < 64; ++d) {
      const float dv = dl2[hh * 64 + d];
      const float* wrow = Wp + (size_t)(hh * 64 + d) * 512 + c0;
      #pragma unroll
      for (int j = 0; j < 16; ++j) acc[j] += dv * wrow[j];
    }
    #pragma unroll
    for (int j = 0; j < 16; ++j) wcorr[hh * 512 + c0 + j] = acc[j];
  }
}

// ========== merged projections: q/k/v (768) | p (256) | corr (64) ==========
__global__ __launch_bounds__(256)
void proj_kernel(const u16* __restrict__ Wstk, const u16* __restrict__ xnT,
                 const u16* __restrict__ posT,
                 const float* __restrict__ bq, const float* __restrict__ ub,
                 const float* __restrict__ bk, const float* __restrict__ bv,
                 const float* __restrict__ wcorr,
                 u16* __restrict__ quB, u16* __restrict__ kB, u16* __restrict__ vB,
                 u16* __restrict__ pB, float* __restrict__ corrOut)
{
  __shared__ float wc[512];
  const int bid = blockIdx.x;
  const int tid = threadIdx.x, w = tid >> 6, lane = tid & 63;
  const int ln16 = lane & 15, kg = lane >> 4;
  if (bid < 768) {
    const int bx = bid & 7;
    const int t = bid >> 3;
    const int my = t % 24;
    const int z = t / 24;
    const int wm = w & 1, wn = w >> 1;
    const int sec = my >> 3;
    const int m0l = (my & 7) * 64 + wm * 32;
    const int n0 = bx * 128 + wn * 64;
    const long XS = (long)TT * CB;
    const long QS = (long)NH * TT * DH;
    const u16* Ar = Wstk + (size_t)(sec * 512 + m0l + ln16) * 512 + kg * 8;
    const u16* Br = xnT + (size_t)z * XS + (size_t)(n0 + ln16) * 512 + kg * 8;
    f32x4 acc[2][4] = {};
    #pragma unroll 2
    for (int ks = 0; ks < 16; ++ks) {
      bf16x8 a[2], bb[4];
      #pragma unroll
      for (int mt = 0; mt < 2; ++mt) a[mt] = ldb8(Ar + (size_t)mt * 16 * 512 + ks * 32);
      #pragma unroll
      for (int nt = 0; nt < 4; ++nt) bb[nt] = ldb8(Br + (size_t)nt * 16 * 512 + ks * 32);
      #pragma unroll
      for (int mt = 0; mt < 2; ++mt)
        #pragma unroll
        for (int nt = 0; nt < 4; ++nt)
          acc[mt][nt] = MFMA16(a[mt], bb[nt], acc[mt][nt]);
    }
    const float scl = (sec == 0) ? ALPHA : 1.f;
    float add[2][4];
    #pragma unroll
    for (int mt = 0; mt < 2; ++mt)
      #pragma unroll
      for (int jr = 0; jr < 4; ++jr) {
        int m = m0l + mt * 16 + kg * 4 + jr;
        add[mt][jr] = (sec == 0) ? (bq[m] + ub[m]) : (sec == 1) ? bk[m] : bv[m];
      }
    if (sec < 2) {
      u16* dst = sec ? kB : quB;
      #pragma unroll
      for (int mt = 0; mt < 2; ++mt)
        #pragma unroll
        for (int nt = 0; nt < 4; ++nt) {
          const int n = n0 + nt * 16 + ln16;
          const int m_low = m0l + mt * 16;
          const size_t o = (size_t)z * QS +
                           ((size_t)(m_low >> 6) * TT + n) * 64 + (m_low & 63) + kg * 4;
          uint2 o2;
          o2.x = cvt2((acc[mt][nt][0] + add[mt][0]) * scl,
                      (acc[mt][nt][1] + add[mt][1]) * scl);
          o2.y = cvt2((acc[mt][nt][2] + add[mt][2]) * scl,
                      (acc[mt][nt][3] + add[mt][3]) * scl);
          *reinterpret_cast<uint2*>(dst + o) = o2;
        }
    } else {
      #pragma unroll
      for (int mt = 0; mt < 2; ++mt)
        #pragma unroll
        for (int nt = 0; nt < 4; ++nt) {
          const int n = n0 + nt * 16 + ln16;
          #pragma unroll
          for (int jr = 0; jr < 4; ++jr)
            vB[(size_t)z * QS + (size_t)(m0l + mt * 16 + kg * 4 + jr) * TT + n] =
                f2b(acc[mt][nt][jr] + add[mt][jr]);
        }
    }
  } else if (bid < 1024) {
    // p projection: pB[h][2048][64] (OMODE-1 layout, no bias)
    const int i = bid - 768;
    const int m0 = (i >> 5) * 64 + (w & 1) * 32;
    const int n0 = (i & 31) * 64 + (w >> 1) * 32;
    const u16* Ar = Wstk + (size_t)(1536 + m0 + ln16) * 512 + kg * 8;
    const u16* Br = posT + (size_t)(n0 + ln16) * 512 + kg * 8;
    f32x4 acc[2][2] = {};
    #pragma unroll 2
    for (int ks = 0; ks < 16; ++ks) {
      bf16x8 a[2], bb[2];
      #pragma unroll
      for (int mt = 0; mt < 2; ++mt) a[mt] = ldb8(Ar + (size_t)mt * 16 * 512 + ks * 32);
      #pragma unroll
      for (int nt = 0; nt < 2; ++nt) bb[nt] = ldb8(Br + (size_t)nt * 16 * 512 + ks * 32);
      #pragma unroll
      for (int mt = 0; mt < 2; ++mt)
        #pragma unroll
        for (int nt = 0; nt < 2; ++nt)
          acc[mt][nt] = MFMA16(a[mt], bb[nt], acc[mt][nt]);
    }
    #pragma unroll
    for (int mt = 0; mt < 2; ++mt)
      #pragma unroll
      for (int nt = 0; nt < 2; ++nt) {
        const int n = n0 + nt * 16 + ln16;
        const int m_low = m0 + mt * 16;
        const size_t o = ((size_t)(m_low >> 6) * 2048 + n) * 64 + (m_low & 63) + kg * 4;
        uint2 o2;
        o2.x = cvt2(acc[mt][nt][0], acc[mt][nt][1]);
        o2.y = cvt2(acc[mt][nt][2], acc[mt][nt][3]);
        *reinterpret_cast<uint2*>(pB + o) = o2;
      }
  } else {
    // corr[h][j] = ALPHA * sum_c wcorr[h][c] * posT[j][c]
    const int i = bid - 1024;
    const int hh = i >> 3;
    const int j = (i & 7) * 256 + tid;
    for (int c = tid; c < 512; c += 256) wc[c] = wcorr[hh * 512 + c];
    __syncthreads();
    const u16* prow = posT + (size_t)j * 512;
    float s = 0.f;
    #pragma unroll 4
    for (int c8 = 0; c8 < 64; ++c8) {
      union { bf16x8 v; u16 u[8]; } pu;
      pu.v = ldb8(prow + c8 * 8);
      #pragma unroll
      for (int e = 0; e < 8; ++e) s += b2f(pu.u[e]) * wc[c8 * 8 + e];
    }
    corrOut[hh * 2048 + j] = s * ALPHA;
  }
}

// ---------- gemm2: wave 32m x 64n, block 64m x 128n (out projection) ----------
template<int K, int OMODE>
__global__ __launch_bounds__(256)
void gemm2(const u16* __restrict__ A, const u16* __restrict__ XT,
           long xStride, long oStride, int Nout,
           const float* __restrict__ b0, void* __restrict__ outv)
{
  const int tid = threadIdx.x, w = tid >> 6, lane = tid & 63;
  const int ln16 = lane & 15, kg = lane >> 4;
  const int wm = w & 1, wn = w >> 1;
  const int m0 = blockIdx.y * 64 + wm * 32;
  const int n0 = blockIdx.x * 128 + wn * 64;
  const int z = blockIdx.z;
  const u16* Ar = A + (size_t)(m0 + ln16) * K + kg * 8;
  const u16* Br = XT + (size_t)z * xStride + (size_t)(n0 + ln16) * K + kg * 8;
  f32x4 acc[2][4] = {};
  #pragma unroll 2
  for (int ks = 0; ks < K / 32; ++ks) {
    bf16x8 a[2], bb[4];
    #pragma unroll
    for (int mt = 0; mt < 2; ++mt) a[mt] = ldb8(Ar + (size_t)mt * 16 * K + ks * 32);
    #pragma unroll
    for (int nt = 0; nt < 4; ++nt) bb[nt] = ldb8(Br + (size_t)nt * 16 * K + ks * 32);
    #pragma unroll
    for (int mt = 0; mt < 2; ++mt)
      #pragma unroll
      for (int nt = 0; nt < 4; ++nt)
        acc[mt][nt] = MFMA16(a[mt], bb[nt], acc[mt][nt]);
  }
  float add[2][4];
  #pragma unroll
  for (int mt = 0; mt < 2; ++mt)
    #pragma unroll
    for (int jr = 0; jr < 4; ++jr)
      add[mt][jr] = b0 ? b0[m0 + mt * 16 + kg * 4 + jr] : 0.f;
  #pragma unroll
  for (int mt = 0; mt < 2; ++mt)
    #pragma unroll
    for (int nt = 0; nt < 4; ++nt) {
      const int n = n0 + nt * 16 + ln16;
      if constexpr (OMODE == 0) {
        float* out = (float*)outv;
        #pragma unroll
        for (int jr = 0; jr < 4; ++jr)
          out[(size_t)z * oStride + (size_t)(m0 + mt * 16 + kg * 4 + jr) * Nout + n] =
              acc[mt][nt][jr] + add[mt][jr];
      } else {
        const int m_low = m0 + mt * 16;
        const size_t o = (size_t)z * oStride +
                         ((size_t)(m_low >> 6) * Nout + n) * 64 + (m_low & 63) + kg * 4;
        uint2 o2;
        o2.x = cvt2(acc[mt][nt][0] + add[mt][0], acc[mt][nt][1] + add[mt][1]);
        o2.y = cvt2(acc[mt][nt][2] + add[mt][2], acc[mt][nt][3] + add[mt][3]);
        *reinterpret_cast<uint2*>((u16*)outv + o) = o2;
      }
    }
}

// ---------- Pass 1 (MFMA): partial l over a ki half (LDS G band; setprio on MFMA) ----------
__global__ __launch_bounds__(256)
void stats_mfma(const u16* __restrict__ qu, const u16* __restrict__ kk_,
                const u16* __restrict__ pp, const float* __restrict__ corr,
                const float* __restrict__ xmask, float* __restrict__ ls)
{
  const int tid = threadIdx.x;
  const int w = tid >> 6, lane = tid & 63;
  const int ln16 = lane & 15, kg = lane >> 4;
  const int bid = blockIdx.x;
  const int bh = (bid & 7) + 8 * ((bid >> 3) & 3);
  const int rest = bid >> 5;
  const int qi0 = (rest & 31) * 32;
  const int part = rest >> 5;
  const int b = bh >> 3, h = bh & 7;
  const u16* quP = qu + (size_t)bh * TT * DH;
  const u16* kP  = kk_ + (size_t)bh * TT * DH;
  const u16* pP  = pp + (size_t)h * 2048 * DH;
  const float* corrP = corr + (h << 11);

  __shared__ u16 G[4][32][100];
  __shared__ float red[4][32];

  bf16x8 qa[2][2];
  #pragma unroll
  for (int mt = 0; mt < 2; ++mt)
    #pragma unroll
    for (int kc = 0; kc < 2; ++kc)
      qa[mt][kc] = ldb8(&quP[(size_t)(qi0 + mt * 16 + ln16) * DH + kc * 32 + kg * 8]);
  float aq[2][4];
  #pragma unroll
  for (int mt = 0; mt < 2; ++mt)
    #pragma unroll
    for (int jr = 0; jr < 4; ++jr)
      aq[mt][jr] = (xmask[b * TT + qi0 + mt * 16 + kg * 4 + jr] - 1.f) * MASKL;

  float rs[2][4] = {};
  for (int c = 0; c < 2; ++c) {
    const int ki0 = (part * 8 + c * 4 + w) * 64;
    const int j0 = ki0 - qi0 + 992;
    __builtin_amdgcn_s_setprio(1);
    #pragma unroll
    for (int nt = 0; nt < 6; ++nt) {
      const size_t po = (size_t)(j0 + nt * 16 + ln16) * DH + kg * 8;
      bf16x8 pb0 = ldb8(&pP[po]);
      bf16x8 pb1 = ldb8(&pP[po + 32]);
      const float cval = corrP[j0 + nt * 16 + ln16];
      #pragma unroll
      for (int mt = 0; mt < 2; ++mt) {
        f32x4 g = {0.f, 0.f, 0.f, 0.f};
        g = MFMA16(qa[mt][0], pb0, g);
        g = MFMA16(qa[mt][1], pb1, g);
        #pragma unroll
        for (int jr = 0; jr < 4; ++jr)
          G[w][mt * 16 + kg * 4 + jr][nt * 16 + ln16] = f2b(g[jr] + cval);
      }
    }
    __builtin_amdgcn_s_setprio(0);
    #pragma unroll
    for (int nt = 0; nt < 4; ++nt) {
      const size_t ko = (size_t)(ki0 + nt * 16 + ln16) * DH + kg * 8;
      bf16x8 kb0 = ldb8(&kP[ko]);
      bf16x8 kb1 = ldb8(&kP[ko + 32]);
      const float ak = (xmask[b * TT + ki0 + nt * 16 + ln16] - 1.f) * MASKL;
      #pragma unroll
      for (int mt = 0; mt < 2; ++mt) {
        f32x4 dd = { aq[mt][0] + ak, aq[mt][1] + ak, aq[mt][2] + ak, aq[mt][3] + ak };
        __builtin_amdgcn_s_setprio(1);
        dd = MFMA16(qa[mt][0], kb0, dd);
        dd = MFMA16(qa[mt][1], kb1, dd);
        __builtin_amdgcn_s_setprio(0);
        #pragma unroll
        for (int jr = 0; jr < 4; ++jr) {
          const int qrow = mt * 16 + kg * 4 + jr;
          const int u = nt * 16 + ln16 - qrow + 31;
          rs[mt][jr] += exp2f(dd[jr] + b2f(G[w][qrow][u]));
        }
      }
    }
  }
  #pragma unroll
  for (int mt = 0; mt < 2; ++mt)
    #pragma unroll
    for (int jr = 0; jr < 4; ++jr) {
      float v = rs[mt][jr];
      v += __shfl_xor(v, 1); v += __shfl_xor(v, 2);
      v += __shfl_xor(v, 4); v += __shfl_xor(v, 8);
      rs[mt][jr] = v;
    }
  if (ln16 == 0) {
    #pragma unroll
    for (int mt = 0; mt < 2; ++mt)
      #pragma unroll
      for (int jr = 0; jr < 4; ++jr)
        red[w][mt * 16 + kg * 4 + jr] = rs[mt][jr];
  }
  __syncthreads();
  if (tid < 32)
    ls[(size_t)part * 32768 + (size_t)bh * TT + qi0 + tid] =
        red[0][tid] + red[1][tid] + red[2][tid] + red[3][tid];
}

// ---------- Pass 2 (MFMA): full-qi ctx; G in registers, P double-buffered ----------
// grid 512: bh=(bid&7)+8*((bid>>3)&3); t0=(bid>>5)*64. 16 serial qi chunks.
// 1/l folded into P (no separate vscale pass). Writes ctxS [b][t][512] directly.
__global__ __launch_bounds__(256)
void ctx_mfma(const u16* __restrict__ qu, const u16* __restrict__ kk_,
              const u16* __restrict__ vv, const u16* __restrict__ pp,
              const float* __restrict__ corr, const float* __restrict__ xmask,
              const float* __restrict__ ls, u16* __restrict__ ctxS)
{
  const int tid = threadIdx.x;
  const int w = tid >> 6, lane = tid & 63;
  const int ln16 = lane & 15, kg = lane >> 4;
  const int l48 = lane & 48;
  const int bid = blockIdx.x;
  const int bh = (bid & 7) + 8 * ((bid >> 3) & 3);
  const int t0 = (bid >> 5) * 64;
  const int b = bh >> 3, h = bh & 7;
  const u16* quP = qu + (size_t)bh * TT * DH;
  const u16* kP  = kk_ + (size_t)bh * TT * DH;
  const u16* vP  = vv + (size_t)bh * DH * TT;
  const u16* pP  = pp + (size_t)h * 2048 * DH;
  const float* corrP = corr + (h << 11);
  const float* lsP = ls + (size_t)bh * TT;

  __shared__ __align__(16) u16 P[2][64][72];   // double-buffered P[t][qi_local]

  bf16x8 ka[4][2];
  #pragma unroll
  for (int nt = 0; nt < 4; ++nt)
    #pragma unroll
    for (int kc = 0; kc < 2; ++kc)
      ka[nt][kc] = ldb8(&kP[(size_t)(t0 + nt * 16 + ln16) * DH + kc * 32 + kg * 8]);
  float at4[4];
  #pragma unroll
  for (int nt = 0; nt < 4; ++nt)
    at4[nt] = (xmask[b * TT + t0 + nt * 16 + ln16] - 1.f) * MASKL;

  // scores for chunk qcn -> P[buf]
  auto scores = [&](int qcn, int buf) {
    const int qw = qcn * 64 + w * 16;
    const int j0 = t0 - qw + 1008;
    const size_t qo = (size_t)(qw + ln16) * DH + kg * 8;
    bf16x8 qa0 = ldb8(&quP[qo]), qa1 = ldb8(&quP[qo + 32]);
    // pos bands in registers (incl corr)
    f32x4 g[5];
    #pragma unroll
    for (int n = 0; n < 5; ++n) {
      const size_t po = (size_t)(j0 + n * 16 + ln16) * DH + kg * 8;
      bf16x8 pb0 = ldb8(&pP[po]), pb1 = ldb8(&pP[po + 32]);
      const float cval = corrP[j0 + n * 16 + ln16];
      f32x4 t = {cval, cval, cval, cval};
      t = MFMA16(qa0, pb0, t);
      t = MFMA16(qa1, pb1, t);
      g[n] = t;
    }
    // gather prep: sg[jr][n] = G[qrow=kg*4+jr][*] shuffled to this lane's columns
    float sg[4][5];
    #pragma unroll
    for (int jr = 0; jr < 4; ++jr) {
      const int qrow = kg * 4 + jr;
      const int src = l48 | ((ln16 + 15 - qrow) & 15);
      #pragma unroll
      for (int n = 0; n < 5; ++n) sg[jr][n] = __shfl(g[n][jr], src);
    }
    float aqv[4], linv[4];
    #pragma unroll
    for (int jr = 0; jr < 4; ++jr) {
      const int qi = qw + kg * 4 + jr;
      aqv[jr] = (xmask[b * TT + qi] - 1.f) * MASKL;
      linv[jr] = __builtin_amdgcn_rcpf(lsP[qi] + lsP[32768 + qi]);
    }
    #pragma unroll
    for (int nt = 0; nt < 4; ++nt) {
      f32x4 dd = { aqv[0] + at4[nt], aqv[1] + at4[nt],
                   aqv[2] + at4[nt], aqv[3] + at4[nt] };
      dd = MFMA16(qa0, ka[nt][0], dd);
      dd = MFMA16(qa1, ka[nt][1], dd);
      float ev[4];
      #pragma unroll
      for (int jr = 0; jr < 4; ++jr) {
        const int qrow = kg * 4 + jr;
        const float val = (ln16 <= qrow) ? sg[jr][nt] : sg[jr][nt + 1];
        ev[jr] = exp2f(dd[jr] + val) * linv[jr];
      }
      uint2 o2;
      o2.x = cvt2(ev[0], ev[1]);
      o2.y = cvt2(ev[2], ev[3]);
      *reinterpret_cast<uint2*>(&P[buf][nt * 16 + ln16][w * 16 + kg * 4]) = o2;
    }
  };

  f32x4 cacc[4] = {};
  scores(0, 0);
  __syncthreads();
  for (int i = 0; i < 16; ++i) {
    // PV from P[i&1]; overlaps with next chunk's scores below (no barrier between)
    const size_t vbase = (size_t)(w * 16 + ln16) * TT + i * 64 + kg * 8;
    bf16x8 vf0 = ldb8(&vP[vbase]), vf1 = ldb8(&vP[vbase + 32]);
    __builtin_amdgcn_s_setprio(1);
    #pragma unroll
    for (int nt = 0; nt < 4; ++nt) {
      bf16x8 pb0 = *reinterpret_cast<const bf16x8*>(&P[i & 1][nt * 16 + ln16][kg * 8]);
      bf16x8 pb1 = *reinterpret_cast<const bf16x8*>(&P[i & 1][nt * 16 + ln16][32 + kg * 8]);
      cacc[nt] = MFMA16(vf0, pb0, cacc[nt]);
      cacc[nt] = MFMA16(vf1, pb1, cacc[nt]);
    }
    __builtin_amdgcn_s_setprio(0);
    if (i < 15) {
      scores(i + 1, (i + 1) & 1);
      __syncthreads();
    }
  }
  #pragma unroll
  for (int nt = 0; nt < 4; ++nt) {
    const int t = t0 + nt * 16 + ln16;
    uint2 o2;
    o2.x = cvt2(cacc[nt][0], cacc[nt][1]);
    o2.y = cvt2(cacc[nt][2], cacc[nt][3]);
    *reinterpret_cast<uint2*>(
      &ctxS[((size_t)b * TT + t) * 512 + h * 64 + w * 16 + kg * 4]) = o2;
  }
}

// ---------- launch ----------
extern "C" void kernel_launch(void* const* d_in, const int* in_sizes, int n_in,
                              void* d_out, int out_size, void* d_ws, size_t ws_size,
                              hipStream_t stream)
{
  (void)in_sizes; (void)n_in; (void)out_size;
  const float* x     = (const float*)d_in[0];
  const float* pe    = (const float*)d_in[1];
  const float* xm    = (const float*)d_in[2];
  const float* gamma = (const float*)d_in[3];
  const float* beta  = (const float*)d_in[4];
  const float* Wq    = (const float*)d_in[5];
  const float* bq    = (const float*)d_in[6];
  const float* Wk    = (const float*)d_in[7];
  const float* bk    = (const float*)d_in[8];
  const float* Wv    = (const float*)d_in[9];
  const float* bv    = (const float*)d_in[10];
  const float* Wp    = (const float*)d_in[11];
  const float* ub    = (const float*)d_in[12];
  const float* vb    = (const float*)d_in[13];
  const float* Wo    = (const float*)d_in[14];
  const float* bo    = (const float*)d_in[15];

  // workspace layout (bytes); ctxS lives in the staging region (xnT/posT/Wstk
  // are dead after proj_kernel) -- it must NOT alias quB, which ctx reads.
  char* ws = (char*)d_ws;
  u16*  quB  = (u16*) (ws + 0);          // [32][1024][64] bf16  (4 MiB)
  u16*  kB   = (u16*) (ws + 4194304);    // [32][1024][64] bf16  (4 MiB)
  u16*  vB   = (u16*) (ws + 8388608);    // [32][64][1024] bf16  (4 MiB)
  u16*  pB   = (u16*) (ws + 12582912);   // [8][2048][64] bf16   (2 MiB)
  float* corrB = (float*)(ws + 14680064);// [8][2048] f32        (64 KiB)
  float* lsB = (float*)(ws + 14745600);  // [2][32][1024] f32    (256 KiB)
  u16*  WoB  = (u16*) (ws + 15007744);   // [512][512] bf16      (512 KiB)
  u16*  ctxS = (u16*) (ws + 15532032);   // [4][1024][512] bf16  (4 MiB; overlays xnT)
  // staging (dead before ctxS is written) in the same region:
  u16*  xnT  = (u16*) (ws + 15532032);   // [4][1024][512] bf16  (4 MiB)
  u16*  posT = (u16*) (ws + 19726336);   // [2048][512] bf16     (2 MiB)
  u16*  Wstk = (u16*) (ws + 21823488);   // [2048][512] bf16     (2 MiB)
  float* wcorrB = (float*)(ws + 23920640); // [8][512] f32       (16 KiB)
  if (ws_size < 32309248) return;

  dim3 blk(256);

  prefix_kernel<<<dim3(1025), blk, 0, stream>>>(
      Wq, Wk, Wv, Wp, Wo, Wstk, WoB, pe, posT, x, gamma, beta, xnT, ub, vb, wcorrB);
  proj_kernel<<<dim3(1088), blk, 0, stream>>>(
      Wstk, xnT, posT, bq, ub, bk, bv, wcorrB, quB, kB, vB, pB, corrB);

  stats_mfma<<<dim3(2048), blk, 0, stream>>>(quB, kB, pB, corrB, xm, lsB);
  ctx_mfma<<<dim3(512), blk, 0, stream>>>(quB, kB, vB, pB, corrB, xm, lsB, ctxS);

  gemm2<512, 0><<<dim3(8, 8, 4), blk, 0, stream>>>(
      WoB, ctxS, (long)TT * CB, (long)CB * TT, TT, bo, (float*)d_out);
}